// Round 9
// baseline (276.413 us; speedup 1.0000x reference)
//
#include <hip/hip_runtime.h>
#include <hip/hip_bf16.h>

typedef __hip_bfloat16 bf16;
typedef __attribute__((ext_vector_type(8))) short bf16x8;  // 8 bf16 (4 VGPRs)
typedef __attribute__((ext_vector_type(4))) float f32x4;

constexpr int Bc  = 2;
constexpr int Sc  = 2048;
constexpr int Dc  = 1024;   // = H * DK
constexpr int Hc  = 16;
constexpr int DKc = 64;

__device__ __forceinline__ float bfbits2f(unsigned short u) {
  return __uint_as_float(((unsigned)u) << 16);
}
__device__ __forceinline__ unsigned short f2bfbits(float x) {
  bf16 h = __float2bfloat16(x);
  return *reinterpret_cast<unsigned short*>(&h);
}
__device__ __forceinline__ void store1_dyn(char* base, size_t ei, int isf32, float v) {
  if (isf32) *reinterpret_cast<float*>(base + ei * 4) = v;
  else       *reinterpret_cast<bf16*>(base + ei * 2) = __float2bfloat16(v);
}
__device__ __forceinline__ float fast_exp2(float x) {
  return __builtin_amdgcn_exp2f(x);
}
// packed pair f32->bf16 (v_cvt_pk_bf16_f32)
__device__ __forceinline__ unsigned pkbf16(float a, float b) {
  __hip_bfloat162 h = __float22bfloat162_rn(make_float2(a, b));
  return *reinterpret_cast<unsigned*>(&h);
}
// pack 8 floats (two float4) -> uint4 of 8 bf16 (memory order preserved)
__device__ __forceinline__ uint4 pack8(const float4& a, const float4& b) {
  uint4 r;
  r.x = pkbf16(a.x, a.y);
  r.y = pkbf16(a.z, a.w);
  r.z = pkbf16(b.x, b.y);
  r.w = pkbf16(b.z, b.w);
  return r;
}
// async global->LDS direct copy, 16 B per lane (gfx950)
__device__ __forceinline__ void gld16(const void* g, void* l) {
  __builtin_amdgcn_global_load_lds(
      (const __attribute__((address_space(1))) unsigned int*)g,
      (__attribute__((address_space(3))) unsigned int*)l, 16, 0, 0);
}

// ===========================================================================
// Fused prep, R9: WEIGHTS + BIASES ONLY (input convert fused into qkv_gemm).
//   id in [0,1024)     : transpose+bf16-ify the 4 weight matrices
//   id in [1024,1028)  : convert the 4 bias vectors (block 1024 writes flag)
// Grid is 1028 in both big-ws and fallback paths.
// ===========================================================================
__global__ __launch_bounds__(256)
void prep_all(const char* __restrict__ W0, const char* __restrict__ W1,
              const char* __restrict__ W2, const char* __restrict__ W3,
              unsigned short* __restrict__ Wt_all,
              const char* __restrict__ b0, const char* __restrict__ b1,
              const char* __restrict__ b2, const char* __restrict__ b3,
              unsigned short* __restrict__ bb_all,
              const char* __restrict__ A0,
              int* __restrict__ flag_out) {
  __shared__ unsigned short T[64][72];
  __shared__ int cnt[256];
  const int id = blockIdx.x;
  const int tid = threadIdx.x;

  // ---- inline dtype detection (deterministic, identical in every block) ----
  {
    const unsigned short* q = reinterpret_cast<const unsigned short*>(A0);
    int c = 0;
    for (int i = tid; i < 2048; i += 256) {
      const unsigned short u = q[i];
      const int e = (u >> 7) & 0xFF;
      if (e >= 134 || e <= 90) ++c;
    }
    cnt[tid] = c;
    __syncthreads();
    for (int s = 128; s > 0; s >>= 1) {
      if (tid < s) cnt[tid] += cnt[tid + s];
      __syncthreads();
    }
  }
  const int dyn = (cnt[0] > 64) ? 1 : 0;

  if (id < 1024) {
    // ---- weight transpose ----
    const int z = id >> 8, rem = id & 255;
    const int n0 = (rem & 15) * 64, k0 = (rem >> 4) * 64;
    const char* W = (z == 0) ? W0 : (z == 1) ? W1 : (z == 2) ? W2 : W3;
    unsigned short* Wt = Wt_all + (size_t)z * Dc * Dc;
    const int r = tid >> 2, c16 = (tid & 3) * 16;

    unsigned short us[16];
    if (dyn) {
      const float4* p = reinterpret_cast<const float4*>(
          W + ((size_t)(k0 + r) * Dc + n0 + c16) * 4);
      const float4 f0 = p[0], f1 = p[1], f2 = p[2], f3 = p[3];
      const float fv[16] = {f0.x, f0.y, f0.z, f0.w, f1.x, f1.y, f1.z, f1.w,
                            f2.x, f2.y, f2.z, f2.w, f3.x, f3.y, f3.z, f3.w};
#pragma unroll
      for (int i = 0; i < 16; ++i) us[i] = f2bfbits(fv[i]);
    } else {
      const ushort4* p = reinterpret_cast<const ushort4*>(
          W + ((size_t)(k0 + r) * Dc + n0 + c16) * 2);
      const ushort4 u0 = p[0], u1 = p[1], u2 = p[2], u3 = p[3];
      us[0] = u0.x;  us[1] = u0.y;  us[2] = u0.z;  us[3] = u0.w;
      us[4] = u1.x;  us[5] = u1.y;  us[6] = u1.z;  us[7] = u1.w;
      us[8] = u2.x;  us[9] = u2.y;  us[10] = u2.z; us[11] = u2.w;
      us[12] = u3.x; us[13] = u3.y; us[14] = u3.z; us[15] = u3.w;
    }
#pragma unroll
    for (int i = 0; i < 16; ++i) T[r][c16 + i] = us[i];
    __syncthreads();

    unsigned vs[8];
#pragma unroll
    for (int i = 0; i < 8; ++i)
      vs[i] = (unsigned)T[c16 + 2 * i][r] | ((unsigned)T[c16 + 2 * i + 1][r] << 16);
    uint4* op = reinterpret_cast<uint4*>(Wt + (size_t)(n0 + r) * Dc + k0 + c16);
    op[0] = make_uint4(vs[0], vs[1], vs[2], vs[3]);
    op[1] = make_uint4(vs[4], vs[5], vs[6], vs[7]);
  } else {
    // ---- bias convert (+ flag publish for later dispatches) ----
    const int x = id - 1024;
    if (x == 0 && tid == 0) flag_out[0] = dyn;
    const char* src = (x == 0) ? b0 : (x == 1) ? b1 : (x == 2) ? b2 : b3;
    for (int i = tid; i < Dc; i += 256) {
      float v = dyn ? reinterpret_cast<const float*>(src)[i]
                    : bfbits2f(reinterpret_cast<const unsigned short*>(src)[i]);
      bb_all[x * Dc + i] = f2bfbits(v);
    }
  }
}

// ===========================================================================
// ASYNC fused QKV MFMA GEMM, R9: raw-input A (dynamic dtype) with in-register
// f32->bf16 convert (pack8) + swizzled ds_write; B via gld16 with pre-swizzled
// source (R8-proven). This fuses prep's input-convert pass into the GEMM:
// saves 48MB read + 24MB write in prep (+24MB re-read here is L2-friendly).
// LDS layout is IDENTICAL to R8's (chunk c at c ^ ((row&7)<<3)), so the
// proven R8 read side is unchanged. ds_write pattern is conflict-free
// (per instruction each bank gets exactly 8x4B = the 1KB/128B minimum).
// A-loads for tile t+1 issue during compute of tile t (T14).
// BK=64, 128x128, grid (32, 8, 3).
// ===========================================================================
__global__ __launch_bounds__(256)
void qkv_gemm_async(const char* __restrict__ A0, const char* __restrict__ A1,
                    const char* __restrict__ A2,
                    const unsigned short* __restrict__ Wt_all,
                    const unsigned short* __restrict__ bias_all,
                    bf16* __restrict__ C0, bf16* __restrict__ C1,
                    bf16* __restrict__ C2, const int* __restrict__ flagp) {
  constexpr int K = Dc, N = Dc;
  __shared__ __align__(16) unsigned short At[128 * 64];
  __shared__ __align__(16) unsigned short Bt[128 * 64];

  const int z = blockIdx.z;
  const char* A = (z == 0) ? A0 : (z == 1) ? A1 : A2;
  bf16* C = (z == 0) ? C0 : (z == 1) ? C1 : C2;
  const float scale = (z == 0) ? 0.18033688011112042f : 1.0f;  // qscale*log2e
  const unsigned short* Wt = Wt_all + (size_t)z * Dc * Dc;
  const unsigned short* bias = bias_all + z * Dc;
  const int af = flagp[0];

  const int tid = threadIdx.x;
  const int m0 = blockIdx.x * 128, n0 = blockIdx.y * 128;
  const int w = tid >> 6, lane = tid & 63;
  const int lo16 = lane & 15, quad = lane >> 4;
  const int wm = (w >> 1) * 64, wn = (w & 1) * 64;

  // ---- A staging: reg-staged raw input, swizzled ds_write ----
  // thread covers row sr = tid>>1, logical cols sh..sh+32 (4 chunks of 8)
  const int sr = tid >> 1, sh = (tid & 1) * 32;
  const int swr = (sr & 7) << 3;           // row XOR swizzle (elements)

  // ---- B staging: linear LDS dest + pre-swizzled global col (R8) ----
  unsigned short* ldsB = &Bt[w * 2048 + lane * 8];
  const int ssw = ((lane & 7) ^ (lane >> 3)) * 8;
  const unsigned short* gB = Wt + (size_t)(n0 + w * 32 + (lane >> 3)) * K + ssw;

  // read-side swizzle (row&7 == lo16&7 for all fragment rows)
  const int rsw = (lo16 & 7) << 3;
  const int c0 = (quad * 8) ^ rsw;          // kk=0 col (elements)
  const int c1 = (32 + quad * 8) ^ rsw;     // kk=1 col

  f32x4 acc[4][4] = {};

  uint4 ua[4];
  auto loadA = [&](int k0) {
#pragma unroll
    for (int j = 0; j < 4; ++j) {
      const int c = sh + j * 8;
      if (af) {
        const float4* p = reinterpret_cast<const float4*>(
            A + ((size_t)(m0 + sr) * K + k0 + c) * 4);
        ua[j] = pack8(p[0], p[1]);
      } else {
        ua[j] = *reinterpret_cast<const uint4*>(
            A + ((size_t)(m0 + sr) * K + k0 + c) * 2);
      }
    }
  };

  loadA(0);

  for (int k0 = 0; k0 < K; k0 += 64) {
    __syncthreads();   // prior iter's frag reads complete
    // ---- commit A regs to swizzled LDS; issue B gld16 ----
#pragma unroll
    for (int j = 0; j < 4; ++j)
      *reinterpret_cast<uint4*>(&At[sr * 64 + ((sh + j * 8) ^ swr)]) = ua[j];
#pragma unroll
    for (int r = 0; r < 4; ++r)
      gld16(gB + (size_t)(r * 8) * K + k0, ldsB + r * 512);
    __syncthreads();   // drains vmcnt (B) + ds_writes visible

    // ---- T14: next A tile's loads fly during compute ----
    if (k0 + 64 < K) loadA(k0 + 64);

#pragma unroll
    for (int kk = 0; kk < 2; ++kk) {
      const int cc = kk ? c1 : c0;
      bf16x8 afr[4], bfr[4];
#pragma unroll
      for (int mt = 0; mt < 4; ++mt)
        afr[mt] = *reinterpret_cast<const bf16x8*>(&At[(wm + mt * 16 + lo16) * 64 + cc]);
#pragma unroll
      for (int nt = 0; nt < 4; ++nt)
        bfr[nt] = *reinterpret_cast<const bf16x8*>(&Bt[(wn + nt * 16 + lo16) * 64 + cc]);
#pragma unroll
      for (int mt = 0; mt < 4; ++mt)
#pragma unroll
        for (int nt = 0; nt < 4; ++nt)
          acc[mt][nt] = __builtin_amdgcn_mfma_f32_16x16x32_bf16(afr[mt], bfr[nt],
                                                                acc[mt][nt], 0, 0, 0);
    }
  }

  float bv[4];
#pragma unroll
  for (int nt = 0; nt < 4; ++nt)
    bv[nt] = bfbits2f(bias[n0 + wn + nt * 16 + lo16]);
#pragma unroll
  for (int mt = 0; mt < 4; ++mt)
#pragma unroll
    for (int r = 0; r < 4; ++r) {
      const int row = m0 + wm + mt * 16 + quad * 4 + r;
#pragma unroll
      for (int nt = 0; nt < 4; ++nt) {
        const int col = n0 + wn + nt * 16 + lo16;
        C[(size_t)row * N + col] = __float2bfloat16((acc[mt][nt][r] + bv[nt]) * scale);
      }
    }
}

// ===========================================================================
// LEGACY fused QKV GEMM (VGPR staging, dynamic dtype) — ws-too-small fallback.
// ===========================================================================
__global__ __launch_bounds__(256)
void qkv_gemm(const char* __restrict__ A0, const char* __restrict__ A1,
              const char* __restrict__ A2, const unsigned short* __restrict__ Wt_all,
              const unsigned short* __restrict__ bias_all,
              bf16* __restrict__ C0, bf16* __restrict__ C1, bf16* __restrict__ C2,
              const int* __restrict__ flagp) {
  constexpr int K = Dc, N = Dc;
  __shared__ __align__(16) unsigned short At[128][32];
  __shared__ __align__(16) unsigned short Bt[128][32];

  const int z = blockIdx.z;
  const char* A = (z == 0) ? A0 : (z == 1) ? A1 : A2;
  bf16* C = (z == 0) ? C0 : (z == 1) ? C1 : C2;
  const float scale = (z == 0) ? 0.18033688011112042f : 1.0f;
  const unsigned short* Wt = Wt_all + (size_t)z * Dc * Dc;
  const unsigned short* bias = bias_all + z * Dc;
  const int af = flagp[0];

  const int tid = threadIdx.x;
  const int m0 = blockIdx.x * 128, n0 = blockIdx.y * 128;
  const int w = tid >> 6, lane = tid & 63;
  const int lo16 = lane & 15, quad = lane >> 4;
  const int wm = (w >> 1) * 64, wn = (w & 1) * 64;
  const int sr = tid >> 1, sh = (tid & 1) * 16;

  f32x4 acc[4][4] = {};

  for (int k0 = 0; k0 < K; k0 += 32) {
    uint4 a_lo, a_hi;
    if (af) {
      const float4* p = reinterpret_cast<const float4*>(
          A + ((size_t)(m0 + sr) * K + k0 + sh) * 4);
      a_lo = pack8(p[0], p[1]);
      a_hi = pack8(p[2], p[3]);
    } else {
      const uint4* p = reinterpret_cast<const uint4*>(
          A + ((size_t)(m0 + sr) * K + k0 + sh) * 2);
      a_lo = p[0];
      a_hi = p[1];
    }
    const uint4* wp = reinterpret_cast<const uint4*>(Wt + (size_t)(n0 + sr) * K + k0 + sh);
    const uint4 b_lo = wp[0], b_hi = wp[1];

    __syncthreads();
    *reinterpret_cast<uint4*>(&At[sr][sh])     = a_lo;
    *reinterpret_cast<uint4*>(&At[sr][sh + 8]) = a_hi;
    *reinterpret_cast<uint4*>(&Bt[sr][sh])     = b_lo;
    *reinterpret_cast<uint4*>(&Bt[sr][sh + 8]) = b_hi;
    __syncthreads();

    bf16x8 afr[4], bfr[4];
#pragma unroll
    for (int mt = 0; mt < 4; ++mt)
      afr[mt] = *reinterpret_cast<const bf16x8*>(&At[wm + mt * 16 + lo16][quad * 8]);
#pragma unroll
    for (int nt = 0; nt < 4; ++nt)
      bfr[nt] = *reinterpret_cast<const bf16x8*>(&Bt[wn + nt * 16 + lo16][quad * 8]);
#pragma unroll
    for (int mt = 0; mt < 4; ++mt)
#pragma unroll
      for (int nt = 0; nt < 4; ++nt)
        acc[mt][nt] = __builtin_amdgcn_mfma_f32_16x16x32_bf16(afr[mt], bfr[nt],
                                                              acc[mt][nt], 0, 0, 0);
  }

  float bv[4];
#pragma unroll
  for (int nt = 0; nt < 4; ++nt)
    bv[nt] = bfbits2f(bias[n0 + wn + nt * 16 + lo16]);
#pragma unroll
  for (int mt = 0; mt < 4; ++mt)
#pragma unroll
    for (int r = 0; r < 4; ++r) {
      const int row = m0 + wm + mt * 16 + quad * 4 + r;
#pragma unroll
      for (int nt = 0; nt < 4; ++nt) {
        const int col = n0 + wn + nt * 16 + lo16;
        C[(size_t)row * N + col] = __float2bfloat16((acc[mt][nt][r] + bv[nt]) * scale);
      }
    }
}

// ===========================================================================
// ASYNC output-projection GEMM — R7-proven version (128x128, BK=32, linear
// LDS, gld16 both operands). Reverted from R8's BK=64 (total regressed).
// ===========================================================================
__global__ __launch_bounds__(256)
void out_gemm_async(const bf16* __restrict__ A, const unsigned short* __restrict__ Wt,
                    const unsigned short* __restrict__ bias, char* __restrict__ C,
                    const int* __restrict__ flagp) {
  constexpr int K = Dc, N = Dc;
  __shared__ __align__(16) unsigned short At[128 * 32];
  __shared__ __align__(16) unsigned short Bt[128 * 32];

  const int cf = flagp[0];
  const int tid = threadIdx.x;
  const int m0 = blockIdx.x * 128, n0 = blockIdx.y * 128;
  const int w = tid >> 6, lane = tid & 63;
  const int lo16 = lane & 15, quad = lane >> 4;
  const int wm = (w >> 1) * 64, wn = (w & 1) * 64;

  unsigned short* ldsA = &At[w * 1024 + lane * 8];
  unsigned short* ldsB = &Bt[w * 1024 + lane * 8];
  const bf16* gA = A + (size_t)(m0 + w * 32 + (lane >> 2)) * K + (lane & 3) * 8;
  const unsigned short* gB = Wt + (size_t)(n0 + w * 32 + (lane >> 2)) * K + (lane & 3) * 8;

  f32x4 acc[4][4] = {};

  for (int k0 = 0; k0 < K; k0 += 32) {
    gld16(gA + k0, ldsA);
    gld16(gA + (size_t)16 * K + k0, ldsA + 512);
    gld16(gB + k0, ldsB);
    gld16(gB + (size_t)16 * K + k0, ldsB + 512);
    __syncthreads();

    bf16x8 afr[4], bfr[4];
#pragma unroll
    for (int mt = 0; mt < 4; ++mt)
      afr[mt] = *reinterpret_cast<const bf16x8*>(&At[(wm + mt * 16 + lo16) * 32 + quad * 8]);
#pragma unroll
    for (int nt = 0; nt < 4; ++nt)
      bfr[nt] = *reinterpret_cast<const bf16x8*>(&Bt[(wn + nt * 16 + lo16) * 32 + quad * 8]);
#pragma unroll
    for (int mt = 0; mt < 4; ++mt)
#pragma unroll
      for (int nt = 0; nt < 4; ++nt)
        acc[mt][nt] = __builtin_amdgcn_mfma_f32_16x16x32_bf16(afr[mt], bfr[nt],
                                                              acc[mt][nt], 0, 0, 0);
    __syncthreads();
  }

  float bv[4];
#pragma unroll
  for (int nt = 0; nt < 4; ++nt)
    bv[nt] = bfbits2f(bias[n0 + wn + nt * 16 + lo16]);
#pragma unroll
  for (int mt = 0; mt < 4; ++mt)
#pragma unroll
    for (int r = 0; r < 4; ++r) {
      const int row = m0 + wm + mt * 16 + quad * 4 + r;
#pragma unroll
      for (int nt = 0; nt < 4; ++nt) {
        const int col = n0 + wn + nt * 16 + lo16;
        store1_dyn(C, (size_t)row * N + col, cf, acc[mt][nt][r] + bv[nt]);
      }
    }
}

// ===========================================================================
// MFMA causal flash attention, R7 split-K schedule (proven, unchanged).
// ===========================================================================
template <int SPLIT>
__global__ __launch_bounds__(256, 2)
void attn_mfma(const bf16* __restrict__ Q, const bf16* __restrict__ K,
               const bf16* __restrict__ V, bf16* __restrict__ O,
               float* __restrict__ P, float* __restrict__ Lp) {
  __shared__ __align__(16) unsigned short Kt[64][72];      // [key][dk]
  __shared__ __align__(16) unsigned short Vt[64][72];      // [dk][key]
  __shared__ __align__(16) unsigned short St[4][32][72];   // per-wave P [q][key]
  __shared__ float Li[4][32];                              // per-wave 1/l

  const int hb = blockIdx.x & 31;
  int c, t0, t1, part;
  if constexpr (SPLIT) {
    const int u = blockIdx.x >> 5;   // 0..23
    if (u < 8)       { c = u;      t0 = 0;     t1 = 2 * c + 2; part = 0; }
    else if (u < 16) { c = 23 - u; t0 = 0;     t1 = c + 1;     part = 1; }
    else             { c = 31 - u; t0 = c + 1; t1 = 2 * c + 2; part = 2; }
  } else {
    const int i = blockIdx.x >> 5, g = i >> 3, r0 = i & 7;
    c = g ? (15 - r0) : r0; t0 = 0; t1 = 2 * (c + 1); part = 0;
  }
  const int b = hb >> 4, h = hb & 15;
  const int q0 = c * 128;
  const int tid = threadIdx.x;
  const int w = tid >> 6;                  // 0..3
  const int lane = tid & 63;
  const int lo16 = lane & 15, quad = lane >> 4;
  const size_t hd = (size_t)h * DKc;

  // staging patterns (256 threads, both roles per thread) — R3 verbatim
  const int kr = tid >> 2, kc = (tid & 3) * 16;         // K copy (2 x 16B)
  const int vk = (tid & 31) * 2, vd0 = (tid >> 5) * 8;  // V transpose

  // Q fragments for the wave's two 16-row groups
  const bf16* qrowA = Q + ((size_t)(b * Sc + q0 + w * 32 + lo16)) * Dc + hd;
  const bf16x8 qa0 = *reinterpret_cast<const bf16x8*>(qrowA + quad * 8);
  const bf16x8 qa1 = *reinterpret_cast<const bf16x8*>(qrowA + 32 + quad * 8);
  const bf16* qrowB = qrowA + (size_t)16 * Dc;
  const bf16x8 qb0 = *reinterpret_cast<const bf16x8*>(qrowB + quad * 8);
  const bf16x8 qb1 = *reinterpret_cast<const bf16x8*>(qrowB + 32 + quad * 8);

  f32x4 oA[4] = {f32x4{0,0,0,0}, f32x4{0,0,0,0}, f32x4{0,0,0,0}, f32x4{0,0,0,0}};
  f32x4 oB[4] = {f32x4{0,0,0,0}, f32x4{0,0,0,0}, f32x4{0,0,0,0}, f32x4{0,0,0,0}};
  float lsA = 0.f, lsB = 0.f;
  const int qgA = q0 + w * 32 + lo16;      // lane's q, group A
  const int qgB = qgA + 16;                // lane's q, group B
  const int qmaxA = q0 + w * 32 + 15;      // group A max q row
  const int qmaxB = qmaxA + 16;            // group B max q row

  const bf16* ksrc = K + ((size_t)(b * Sc + kr)) * Dc + hd + kc;
  const bf16* vsrc = V + ((size_t)(b * Sc + vk)) * Dc + hd + vd0;

  // ---- prologue: tile-t0 loads into registers ----
  const size_t off0 = (size_t)t0 * 64 * Dc;
  uint4 rKa = *reinterpret_cast<const uint4*>(ksrc + off0);
  uint4 rKb = *reinterpret_cast<const uint4*>(ksrc + off0 + 8);
  uint4 rVa = *reinterpret_cast<const uint4*>(vsrc + off0);
  uint4 rVb = *reinterpret_cast<const uint4*>(vsrc + off0 + Dc);

  for (int t = t0; t < t1; ++t) {
    const int kt = t * 64;
    __syncthreads();   // prior iter's frag reads complete
    // ---- commit staged registers to LDS ----
    *reinterpret_cast<uint4*>(&Kt[kr][kc])     = rKa;
    *reinterpret_cast<uint4*>(&Kt[kr][kc + 8]) = rKb;
    *reinterpret_cast<unsigned*>(&Vt[vd0 + 0][vk]) = (rVa.x & 0xffffu) | (rVb.x << 16);
    *reinterpret_cast<unsigned*>(&Vt[vd0 + 1][vk]) = (rVa.x >> 16)     | (rVb.x & 0xffff0000u);
    *reinterpret_cast<unsigned*>(&Vt[vd0 + 2][vk]) = (rVa.y & 0xffffu) | (rVb.y << 16);
    *reinterpret_cast<unsigned*>(&Vt[vd0 + 3][vk]) = (rVa.y >> 16)     | (rVb.y & 0xffff0000u);
    *reinterpret_cast<unsigned*>(&Vt[vd0 + 4][vk]) = (rVa.z & 0xffffu) | (rVb.z << 16);
    *reinterpret_cast<unsigned*>(&Vt[vd0 + 5][vk]) = (rVa.z >> 16)     | (rVb.z & 0xffff0000u);
    *reinterpret_cast<unsigned*>(&Vt[vd0 + 6][vk]) = (rVa.w & 0xffffu) | (rVb.w << 16);
    *reinterpret_cast<unsigned*>(&Vt[vd0 + 7][vk]) = (rVa.w >> 16)     | (rVb.w & 0xffff0000u);
    __syncthreads();

    // ---- T14: next tile's loads fly during compute ----
    if (t + 1 < t1) {
      const size_t off = (size_t)(t + 1) * 64 * Dc;
      rKa = *reinterpret_cast<const uint4*>(ksrc + off);
      rKb = *reinterpret_cast<const uint4*>(ksrc + off + 8);
      rVa = *reinterpret_cast<const uint4*>(vsrc + off);
      rVb = *reinterpret_cast<const uint4*>(vsrc + off + Dc);
    }

    if (kt > qmaxB) continue;   // whole wave masked (barriers already passed)
    const bool liveA = (kt <= qmaxA);

    // ---- K fragments from LDS, shared by both q-groups ----
    bf16x8 ka[4], kb[4];
#pragma unroll
    for (int ct = 0; ct < 4; ++ct) {
      ka[ct] = *reinterpret_cast<const bf16x8*>(&Kt[ct * 16 + lo16][quad * 8]);
      kb[ct] = *reinterpret_cast<const bf16x8*>(&Kt[ct * 16 + lo16][32 + quad * 8]);
    }

    // ---- S^T = K Q^T for both groups ----
    f32x4 sA[4] = {f32x4{0,0,0,0}, f32x4{0,0,0,0}, f32x4{0,0,0,0}, f32x4{0,0,0,0}};
    f32x4 sB[4] = {f32x4{0,0,0,0}, f32x4{0,0,0,0}, f32x4{0,0,0,0}, f32x4{0,0,0,0}};
    __builtin_amdgcn_s_setprio(1);
#pragma unroll
    for (int ct = 0; ct < 4; ++ct) {
      sB[ct] = __builtin_amdgcn_mfma_f32_16x16x32_bf16(ka[ct], qb0, sB[ct], 0, 0, 0);
      sB[ct] = __builtin_amdgcn_mfma_f32_16x16x32_bf16(kb[ct], qb1, sB[ct], 0, 0, 0);
    }
    if (liveA) {
#pragma unroll
      for (int ct = 0; ct < 4; ++ct) {
        sA[ct] = __builtin_amdgcn_mfma_f32_16x16x32_bf16(ka[ct], qa0, sA[ct], 0, 0, 0);
        sA[ct] = __builtin_amdgcn_mfma_f32_16x16x32_bf16(kb[ct], qa1, sA[ct], 0, 0, 0);
      }
    }
    __builtin_amdgcn_s_setprio(0);

    // ---- causal mask: only diagonal-adjacent tiles (wave-uniform tests) ----
    if (kt + 63 > q0 + w * 32 + 16) {   // group B
#pragma unroll
      for (int ct = 0; ct < 4; ++ct)
#pragma unroll
        for (int r = 0; r < 4; ++r)
          if (kt + ct * 16 + quad * 4 + r > qgB) sB[ct][r] = -1e9f;
    }
    if (liveA && (kt + 63 > q0 + w * 32)) {   // group A
#pragma unroll
      for (int ct = 0; ct < 4; ++ct)
#pragma unroll
        for (int r = 0; r < 4; ++r)
          if (kt + ct * 16 + quad * 4 + r > qgA) sA[ct][r] = -1e9f;
    }

    // ---- unnormalized softmax: p = exp2(s) ----
#pragma unroll
    for (int ct = 0; ct < 4; ++ct) {
      const float p0 = fast_exp2(sB[ct][0]);
      const float p1 = fast_exp2(sB[ct][1]);
      const float p2 = fast_exp2(sB[ct][2]);
      const float p3 = fast_exp2(sB[ct][3]);
      lsB += (p0 + p1) + (p2 + p3);
      uint2 pk;
      pk.x = pkbf16(p0, p1);
      pk.y = pkbf16(p2, p3);
      *reinterpret_cast<uint2*>(&St[w][16 + lo16][ct * 16 + quad * 4]) = pk;
    }
    if (liveA) {
#pragma unroll
      for (int ct = 0; ct < 4; ++ct) {
        const float p0 = fast_exp2(sA[ct][0]);
        const float p1 = fast_exp2(sA[ct][1]);
        const float p2 = fast_exp2(sA[ct][2]);
        const float p3 = fast_exp2(sA[ct][3]);
        lsA += (p0 + p1) + (p2 + p3);
        uint2 pk;
        pk.x = pkbf16(p0, p1);
        pk.y = pkbf16(p2, p3);
        *reinterpret_cast<uint2*>(&St[w][lo16][ct * 16 + quad * 4]) = pk;
      }
    }

    // ---- PV: V fragments shared by both groups ----
    const bf16x8 pb0 = *reinterpret_cast<const bf16x8*>(&St[w][16 + lo16][quad * 8]);
    const bf16x8 pb1 = *reinterpret_cast<const bf16x8*>(&St[w][16 + lo16][32 + quad * 8]);
    const bf16x8 pa0 = *reinterpret_cast<const bf16x8*>(&St[w][lo16][quad * 8]);
    const bf16x8 pa1 = *reinterpret_cast<const bf16x8*>(&St[w][lo16][32 + quad * 8]);
    __builtin_amdgcn_s_setprio(1);
#pragma unroll
    for (int ct = 0; ct < 4; ++ct) {
      const bf16x8 vb0 = *reinterpret_cast<const bf16x8*>(&Vt[ct * 16 + lo16][quad * 8]);
      const bf16x8 vb1 = *reinterpret_cast<const bf16x8*>(&Vt[ct * 16 + lo16][32 + quad * 8]);
      oB[ct] = __builtin_amdgcn_mfma_f32_16x16x32_bf16(pb0, vb0, oB[ct], 0, 0, 0);
      oB[ct] = __builtin_amdgcn_mfma_f32_16x16x32_bf16(pb1, vb1, oB[ct], 0, 0, 0);
      if (liveA) {
        oA[ct] = __builtin_amdgcn_mfma_f32_16x16x32_bf16(pa0, vb0, oA[ct], 0, 0, 0);
        oA[ct] = __builtin_amdgcn_mfma_f32_16x16x32_bf16(pa1, vb1, oA[ct], 0, 0, 0);
      }
    }
    __builtin_amdgcn_s_setprio(0);
  }

  // ---- per-group l reduction (butterfly: every lane gets its column's sum) ----
  lsA += __shfl_xor(lsA, 16);
  lsA += __shfl_xor(lsA, 32);
  lsB += __shfl_xor(lsB, 16);
  lsB += __shfl_xor(lsB, 32);

  if (SPLIT && part != 0) {
    // ---- partial epilogue: raw f32 O + l to workspace (merged later) ----
    float* Pp = P + ((size_t)(part - 1) * 32 + hb) * (size_t)(1024 * 64);
    float* Lq = Lp + ((size_t)(part - 1) * 32 + hb) * 1024;
    const int qlA = q0 - 1024 + w * 32;    // partial chunks have q0 >= 1024
    if (quad == 0) {
      Lq[qlA + lo16] = lsA;
      Lq[qlA + 16 + lo16] = lsB;
    }
#pragma unroll
    for (int r = 0; r < 4; ++r) {
      float* pA = Pp + (size_t)(qlA + quad * 4 + r) * 64 + lo16;
      float* pB = Pp + (size_t)(qlA + 16 + quad * 4 + r) * 64 + lo16;
#pragma unroll
      for (int ct = 0; ct < 4; ++ct) {
        pA[ct * 16] = oA[ct][r];
        pB[ct * 16] = oB[ct][r];
      }
    }
    return;
  }

  // ---- direct epilogue (R3 verbatim) ----
  if (quad == 0) {
    Li[w][lo16] = 1.f / lsA;
    Li[w][16 + lo16] = 1.f / lsB;
  }
  __builtin_amdgcn_wave_barrier();
  const f32x4 invA = *reinterpret_cast<const f32x4*>(&Li[w][quad * 4]);
  const f32x4 invB = *reinterpret_cast<const f32x4*>(&Li[w][16 + quad * 4]);

#pragma unroll
  for (int r = 0; r < 4; ++r) {
    bf16* opA = O + (((size_t)(b * Hc + h) * Sc) + q0 + w * 32 + quad * 4 + r) * DKc + lo16;
    bf16* opB = opA + (size_t)16 * DKc;
#pragma unroll
    for (int ct = 0; ct < 4; ++ct) {
      opA[ct * 16] = __float2bfloat16(oA[ct][r] * invA[r]);
      opB[ct * 16] = __float2bfloat16(oB[ct][r] * invB[r]);
    }
  }
}

// ===========================================================================
// Merge the two k-half partials for chunks 8..15 (q in [1024,2048)):
// att[hb][1024+q][d] = (P0 + P1) / (l0 + l1). 2048 blocks x 256 thr x 4 elems.
// ===========================================================================
__global__ __launch_bounds__(256)
void merge_att(const float* __restrict__ P, const float* __restrict__ Lp,
               bf16* __restrict__ att) {
  const int e = blockIdx.x * 256 + threadIdx.x;   // 0 .. 524287
  const int d4 = (e & 15) * 4;
  const int q  = (e >> 4) & 1023;
  const int hb = e >> 14;                         // 0..31
  const size_t pi = ((size_t)hb * 1024 + q) * 64 + d4;
  const float4 a = *reinterpret_cast<const float4*>(P + pi);
  const float4 c = *reinterpret_cast<const float4*>(P + (size_t)2097152 + pi);
  const float inv = 1.f / (Lp[hb * 1024 + q] + Lp[32768 + hb * 1024 + q]);
  uint2 o;
  o.x = pkbf16((a.x + c.x) * inv, (a.y + c.y) * inv);
  o.y = pkbf16((a.z + c.z) * inv, (a.w + c.w) * inv);
  *reinterpret_cast<uint2*>(att + ((size_t)hb * 2048 + 1024 + q) * 64 + d4) = o;
}

// ===========================================================================
extern "C" void kernel_launch(void* const* d_in, const int* in_sizes, int n_in,
                              void* d_out, int out_size, void* d_ws, size_t ws_size,
                              hipStream_t stream) {
  (void)in_sizes; (void)out_size;
  const char* query = (const char*)d_in[0];
  const char* key_  = (const char*)d_in[1];
  const char* value = (const char*)d_in[2];
  const int wb = n_in - 8;   // weights/biases are the last 8 inputs
  const char* Wq = (const char*)d_in[wb + 0];
  const char* bq = (const char*)d_in[wb + 1];
  const char* Wk = (const char*)d_in[wb + 2];
  const char* bk = (const char*)d_in[wb + 3];
  const char* Wv = (const char*)d_in[wb + 4];
  const char* bv = (const char*)d_in[wb + 5];
  const char* Wo = (const char*)d_in[wb + 6];
  const char* bo = (const char*)d_in[wb + 7];

  char* ws = (char*)d_ws;
  bf16* Qs  = (bf16*)(ws);                         // 8 MiB
  bf16* Ks  = (bf16*)(ws + ((size_t)8  << 20));    // 8 MiB
  bf16* Vs  = (bf16*)(ws + ((size_t)16 << 20));    // 8 MiB
  bf16* att = (bf16*)(ws + ((size_t)24 << 20));    // 8 MiB
  unsigned short* Wt_all = (unsigned short*)(ws + ((size_t)32 << 20));  // 4 x 2 MiB
  unsigned short* bb_all = (unsigned short*)(ws + ((size_t)40 << 20));  // 8 KiB
  int* flag = (int*)(ws + ((size_t)40 << 20) + 16384);
  // attn split-K partials live past 42 MiB (region unused by anything else):
  float* Pw = (float*)(ws + ((size_t)42 << 20));   // 2 x 8.39 MiB f32
  float* Lw = (float*)(ws + ((size_t)59 << 20));   // 2 x 128 KiB f32
  const bool big_ws = ws_size >= ((size_t)66 << 20);

  prep_all<<<1028, 256, 0, stream>>>(Wq, Wk, Wv, Wo, Wt_all, bq, bk, bv, bo,
                                     bb_all, query, flag);

  if (big_ws) {
    qkv_gemm_async<<<dim3(32, 8, 3), 256, 0, stream>>>(query, key_, value,
                                                       Wt_all, bb_all,
                                                       Qs, Ks, Vs, flag);
    attn_mfma<1><<<dim3(768), 256, 0, stream>>>(Qs, Ks, Vs, att, Pw, Lw);
    merge_att<<<dim3(2048), 256, 0, stream>>>(Pw, Lw, att);
  } else {
    qkv_gemm<<<dim3(32, 8, 3), 256, 0, stream>>>(query, key_, value, Wt_all, bb_all,
                                                 Qs, Ks, Vs, flag);
    attn_mfma<0><<<dim3(512), 256, 0, stream>>>(Qs, Ks, Vs, att, Pw, Lw);
  }

  out_gemm_async<<<dim3(32, 8), 256, 0, stream>>>(att, Wt_all + (size_t)3 * Dc * Dc,
                                                  bb_all + 3 * Dc, (char*)d_out, flag);
}

// Round 10
// 228.609 us; speedup vs baseline: 1.2091x; 1.2091x over previous
//
#include <hip/hip_runtime.h>
#include <hip/hip_bf16.h>

typedef __hip_bfloat16 bf16;
typedef __attribute__((ext_vector_type(8))) short bf16x8;  // 8 bf16 (4 VGPRs)
typedef __attribute__((ext_vector_type(4))) float f32x4;

constexpr int Bc  = 2;
constexpr int Sc  = 2048;
constexpr int Dc  = 1024;   // = H * DK
constexpr int Hc  = 16;
constexpr int DKc = 64;

__device__ __forceinline__ float bfbits2f(unsigned short u) {
  return __uint_as_float(((unsigned)u) << 16);
}
__device__ __forceinline__ unsigned short f2bfbits(float x) {
  bf16 h = __float2bfloat16(x);
  return *reinterpret_cast<unsigned short*>(&h);
}
__device__ __forceinline__ void store1_dyn(char* base, size_t ei, int isf32, float v) {
  if (isf32) *reinterpret_cast<float*>(base + ei * 4) = v;
  else       *reinterpret_cast<bf16*>(base + ei * 2) = __float2bfloat16(v);
}
__device__ __forceinline__ float fast_exp2(float x) {
  return __builtin_amdgcn_exp2f(x);
}
// packed pair f32->bf16 (v_cvt_pk_bf16_f32)
__device__ __forceinline__ unsigned pkbf16(float a, float b) {
  __hip_bfloat162 h = __float22bfloat162_rn(make_float2(a, b));
  return *reinterpret_cast<unsigned*>(&h);
}
// pack 8 floats (two float4) -> uint4 of 8 bf16 (memory order preserved)
__device__ __forceinline__ uint4 pack8(const float4& a, const float4& b) {
  uint4 r;
  r.x = pkbf16(a.x, a.y);
  r.y = pkbf16(a.z, a.w);
  r.z = pkbf16(b.x, b.y);
  r.w = pkbf16(b.z, b.w);
  return r;
}
// async global->LDS direct copy, 16 B per lane (gfx950)
__device__ __forceinline__ void gld16(const void* g, void* l) {
  __builtin_amdgcn_global_load_lds(
      (const __attribute__((address_space(1))) unsigned int*)g,
      (__attribute__((address_space(3))) unsigned int*)l, 16, 0, 0);
}

// ===========================================================================
// Fused prep (R7-proven): detect folded in; every block votes locally.
//   id in [0,1024)     : transpose+bf16-ify the 4 weight matrices
//   id in [1024,1028)  : convert the 4 bias vectors (block 1024 writes flag)
//   id in [1028,2564)  : convert q/k/v inputs to bf16
// Fallback grid 1028 covers transpose + bias (and flag).
// ===========================================================================
__global__ __launch_bounds__(256)
void prep_all(const char* __restrict__ W0, const char* __restrict__ W1,
              const char* __restrict__ W2, const char* __restrict__ W3,
              unsigned short* __restrict__ Wt_all,
              const char* __restrict__ b0, const char* __restrict__ b1,
              const char* __restrict__ b2, const char* __restrict__ b3,
              unsigned short* __restrict__ bb_all,
              const char* __restrict__ A0, const char* __restrict__ A1,
              const char* __restrict__ A2, bf16* __restrict__ B0,
              bf16* __restrict__ B1, bf16* __restrict__ B2,
              int* __restrict__ flag_out) {
  __shared__ unsigned short T[64][72];
  __shared__ int cnt[256];
  const int id = blockIdx.x;
  const int tid = threadIdx.x;

  // ---- inline dtype detection (deterministic, identical in every block) ----
  {
    const unsigned short* q = reinterpret_cast<const unsigned short*>(A0);
    int c = 0;
    for (int i = tid; i < 2048; i += 256) {
      const unsigned short u = q[i];
      const int e = (u >> 7) & 0xFF;
      if (e >= 134 || e <= 90) ++c;
    }
    cnt[tid] = c;
    __syncthreads();
    for (int s = 128; s > 0; s >>= 1) {
      if (tid < s) cnt[tid] += cnt[tid + s];
      __syncthreads();
    }
  }
  const int dyn = (cnt[0] > 64) ? 1 : 0;

  if (id < 1024) {
    // ---- weight transpose ----
    const int z = id >> 8, rem = id & 255;
    const int n0 = (rem & 15) * 64, k0 = (rem >> 4) * 64;
    const char* W = (z == 0) ? W0 : (z == 1) ? W1 : (z == 2) ? W2 : W3;
    unsigned short* Wt = Wt_all + (size_t)z * Dc * Dc;
    const int r = tid >> 2, c16 = (tid & 3) * 16;

    unsigned short us[16];
    if (dyn) {
      const float4* p = reinterpret_cast<const float4*>(
          W + ((size_t)(k0 + r) * Dc + n0 + c16) * 4);
      const float4 f0 = p[0], f1 = p[1], f2 = p[2], f3 = p[3];
      const float fv[16] = {f0.x, f0.y, f0.z, f0.w, f1.x, f1.y, f1.z, f1.w,
                            f2.x, f2.y, f2.z, f2.w, f3.x, f3.y, f3.z, f3.w};
#pragma unroll
      for (int i = 0; i < 16; ++i) us[i] = f2bfbits(fv[i]);
    } else {
      const ushort4* p = reinterpret_cast<const ushort4*>(
          W + ((size_t)(k0 + r) * Dc + n0 + c16) * 2);
      const ushort4 u0 = p[0], u1 = p[1], u2 = p[2], u3 = p[3];
      us[0] = u0.x;  us[1] = u0.y;  us[2] = u0.z;  us[3] = u0.w;
      us[4] = u1.x;  us[5] = u1.y;  us[6] = u1.z;  us[7] = u1.w;
      us[8] = u2.x;  us[9] = u2.y;  us[10] = u2.z; us[11] = u2.w;
      us[12] = u3.x; us[13] = u3.y; us[14] = u3.z; us[15] = u3.w;
    }
#pragma unroll
    for (int i = 0; i < 16; ++i) T[r][c16 + i] = us[i];
    __syncthreads();

    unsigned vs[8];
#pragma unroll
    for (int i = 0; i < 8; ++i)
      vs[i] = (unsigned)T[c16 + 2 * i][r] | ((unsigned)T[c16 + 2 * i + 1][r] << 16);
    uint4* op = reinterpret_cast<uint4*>(Wt + (size_t)(n0 + r) * Dc + k0 + c16);
    op[0] = make_uint4(vs[0], vs[1], vs[2], vs[3]);
    op[1] = make_uint4(vs[4], vs[5], vs[6], vs[7]);
  } else if (id < 1028) {
    // ---- bias convert (+ flag publish for later dispatches) ----
    const int x = id - 1024;
    if (x == 0 && tid == 0) flag_out[0] = dyn;
    const char* src = (x == 0) ? b0 : (x == 1) ? b1 : (x == 2) ? b2 : b3;
    for (int i = tid; i < Dc; i += 256) {
      float v = dyn ? reinterpret_cast<const float*>(src)[i]
                    : bfbits2f(reinterpret_cast<const unsigned short*>(src)[i]);
      bb_all[x * Dc + i] = f2bfbits(v);
    }
  } else {
    // ---- q/k/v convert ----
    const int j = id - 1028;
    const int z = j >> 9, x = j & 511;
    const char* src = (z == 0) ? A0 : (z == 1) ? A1 : A2;
    bf16* dst = (z == 0) ? B0 : (z == 1) ? B1 : B2;
    const size_t n = (size_t)4096 * Dc;
    const size_t stride = (size_t)512 * 256 * 8;
    for (size_t i = ((size_t)x * 256 + tid) * 8; i < n; i += stride) {
      uint4 u;
      if (dyn) {
        const float4* p = reinterpret_cast<const float4*>(src + i * 4);
        u = pack8(p[0], p[1]);
      } else {
        u = *reinterpret_cast<const uint4*>(src + i * 2);
      }
      *reinterpret_cast<uint4*>(dst + i) = u;
    }
  }
}

// ===========================================================================
// ASYNC fused QKV MFMA GEMM — R8-proven (41.2us, 0 bank conflicts):
// BK=64 + T2 XOR-swizzled LDS; bf16 inputs via gld16 with pre-swizzled
// source col; read col XORs ((row&7)<<3). 128x128, grid (32,8,3).
// ===========================================================================
__global__ __launch_bounds__(256)
void qkv_gemm_async(const bf16* __restrict__ A0, const bf16* __restrict__ A1,
                    const bf16* __restrict__ A2,
                    const unsigned short* __restrict__ Wt_all,
                    const unsigned short* __restrict__ bias_all,
                    bf16* __restrict__ C0, bf16* __restrict__ C1,
                    bf16* __restrict__ C2) {
  constexpr int K = Dc, N = Dc;
  __shared__ __align__(16) unsigned short At[128 * 64];
  __shared__ __align__(16) unsigned short Bt[128 * 64];

  const int z = blockIdx.z;
  const bf16* A = (z == 0) ? A0 : (z == 1) ? A1 : A2;
  bf16* C = (z == 0) ? C0 : (z == 1) ? C1 : C2;
  const float scale = (z == 0) ? 0.18033688011112042f : 1.0f;  // qscale*log2e
  const unsigned short* Wt = Wt_all + (size_t)z * Dc * Dc;
  const unsigned short* bias = bias_all + z * Dc;

  const int tid = threadIdx.x;
  const int m0 = blockIdx.x * 128, n0 = blockIdx.y * 128;
  const int w = tid >> 6, lane = tid & 63;
  const int lo16 = lane & 15, quad = lane >> 4;
  const int wm = (w >> 1) * 64, wn = (w & 1) * 64;

  // linear LDS dest (wave-uniform base + lane*16B), pre-swizzled global col
  unsigned short* ldsA = &At[w * 2048 + lane * 8];
  unsigned short* ldsB = &Bt[w * 2048 + lane * 8];
  const int ssw = ((lane & 7) ^ (lane >> 3)) * 8;      // source col swizzle
  const bf16* gA = A + (size_t)(m0 + w * 32 + (lane >> 3)) * K + ssw;
  const unsigned short* gB = Wt + (size_t)(n0 + w * 32 + (lane >> 3)) * K + ssw;

  // read-side swizzle (row&7 == lo16&7 for all fragment rows)
  const int rsw = (lo16 & 7) << 3;
  const int c0 = (quad * 8) ^ rsw;          // kk=0 col (elements)
  const int c1 = (32 + quad * 8) ^ rsw;     // kk=1 col

  f32x4 acc[4][4] = {};

  for (int k0 = 0; k0 < K; k0 += 64) {
#pragma unroll
    for (int r = 0; r < 4; ++r) {
      gld16(gA + (size_t)(r * 8) * K + k0, ldsA + r * 512);
      gld16(gB + (size_t)(r * 8) * K + k0, ldsB + r * 512);
    }
    __syncthreads();   // drains vmcnt -> LDS tile ready

#pragma unroll
    for (int kk = 0; kk < 2; ++kk) {
      const int cc = kk ? c1 : c0;
      bf16x8 afr[4], bfr[4];
#pragma unroll
      for (int mt = 0; mt < 4; ++mt)
        afr[mt] = *reinterpret_cast<const bf16x8*>(&At[(wm + mt * 16 + lo16) * 64 + cc]);
#pragma unroll
      for (int nt = 0; nt < 4; ++nt)
        bfr[nt] = *reinterpret_cast<const bf16x8*>(&Bt[(wn + nt * 16 + lo16) * 64 + cc]);
#pragma unroll
      for (int mt = 0; mt < 4; ++mt)
#pragma unroll
        for (int nt = 0; nt < 4; ++nt)
          acc[mt][nt] = __builtin_amdgcn_mfma_f32_16x16x32_bf16(afr[mt], bfr[nt],
                                                                acc[mt][nt], 0, 0, 0);
    }
    __syncthreads();   // frag reads done before next iter's gld overwrite
  }

  float bv[4];
#pragma unroll
  for (int nt = 0; nt < 4; ++nt)
    bv[nt] = bfbits2f(bias[n0 + wn + nt * 16 + lo16]);
#pragma unroll
  for (int mt = 0; mt < 4; ++mt)
#pragma unroll
    for (int r = 0; r < 4; ++r) {
      const int row = m0 + wm + mt * 16 + quad * 4 + r;
#pragma unroll
      for (int nt = 0; nt < 4; ++nt) {
        const int col = n0 + wn + nt * 16 + lo16;
        C[(size_t)row * N + col] = __float2bfloat16((acc[mt][nt][r] + bv[nt]) * scale);
      }
    }
}

// ===========================================================================
// LEGACY fused QKV GEMM (VGPR staging, dynamic dtype) — ws-too-small fallback.
// ===========================================================================
__global__ __launch_bounds__(256)
void qkv_gemm(const char* __restrict__ A0, const char* __restrict__ A1,
              const char* __restrict__ A2, const unsigned short* __restrict__ Wt_all,
              const unsigned short* __restrict__ bias_all,
              bf16* __restrict__ C0, bf16* __restrict__ C1, bf16* __restrict__ C2,
              const int* __restrict__ flagp) {
  constexpr int K = Dc, N = Dc;
  __shared__ __align__(16) unsigned short At[128][32];
  __shared__ __align__(16) unsigned short Bt[128][32];

  const int z = blockIdx.z;
  const char* A = (z == 0) ? A0 : (z == 1) ? A1 : A2;
  bf16* C = (z == 0) ? C0 : (z == 1) ? C1 : C2;
  const float scale = (z == 0) ? 0.18033688011112042f : 1.0f;
  const unsigned short* Wt = Wt_all + (size_t)z * Dc * Dc;
  const unsigned short* bias = bias_all + z * Dc;
  const int af = flagp[0];

  const int tid = threadIdx.x;
  const int m0 = blockIdx.x * 128, n0 = blockIdx.y * 128;
  const int w = tid >> 6, lane = tid & 63;
  const int lo16 = lane & 15, quad = lane >> 4;
  const int wm = (w >> 1) * 64, wn = (w & 1) * 64;
  const int sr = tid >> 1, sh = (tid & 1) * 16;

  f32x4 acc[4][4] = {};

  for (int k0 = 0; k0 < K; k0 += 32) {
    uint4 a_lo, a_hi;
    if (af) {
      const float4* p = reinterpret_cast<const float4*>(
          A + ((size_t)(m0 + sr) * K + k0 + sh) * 4);
      a_lo = pack8(p[0], p[1]);
      a_hi = pack8(p[2], p[3]);
    } else {
      const uint4* p = reinterpret_cast<const uint4*>(
          A + ((size_t)(m0 + sr) * K + k0 + sh) * 2);
      a_lo = p[0];
      a_hi = p[1];
    }
    const uint4* wp = reinterpret_cast<const uint4*>(Wt + (size_t)(n0 + sr) * K + k0 + sh);
    const uint4 b_lo = wp[0], b_hi = wp[1];

    __syncthreads();
    *reinterpret_cast<uint4*>(&At[sr][sh])     = a_lo;
    *reinterpret_cast<uint4*>(&At[sr][sh + 8]) = a_hi;
    *reinterpret_cast<uint4*>(&Bt[sr][sh])     = b_lo;
    *reinterpret_cast<uint4*>(&Bt[sr][sh + 8]) = b_hi;
    __syncthreads();

    bf16x8 afr[4], bfr[4];
#pragma unroll
    for (int mt = 0; mt < 4; ++mt)
      afr[mt] = *reinterpret_cast<const bf16x8*>(&At[wm + mt * 16 + lo16][quad * 8]);
#pragma unroll
    for (int nt = 0; nt < 4; ++nt)
      bfr[nt] = *reinterpret_cast<const bf16x8*>(&Bt[wn + nt * 16 + lo16][quad * 8]);
#pragma unroll
    for (int mt = 0; mt < 4; ++mt)
#pragma unroll
      for (int nt = 0; nt < 4; ++nt)
        acc[mt][nt] = __builtin_amdgcn_mfma_f32_16x16x32_bf16(afr[mt], bfr[nt],
                                                              acc[mt][nt], 0, 0, 0);
  }

  float bv[4];
#pragma unroll
  for (int nt = 0; nt < 4; ++nt)
    bv[nt] = bfbits2f(bias[n0 + wn + nt * 16 + lo16]);
#pragma unroll
  for (int mt = 0; mt < 4; ++mt)
#pragma unroll
    for (int r = 0; r < 4; ++r) {
      const int row = m0 + wm + mt * 16 + quad * 4 + r;
#pragma unroll
      for (int nt = 0; nt < 4; ++nt) {
        const int col = n0 + wn + nt * 16 + lo16;
        C[(size_t)row * N + col] = __float2bfloat16((acc[mt][nt][r] + bv[nt]) * scale);
      }
    }
}

// ===========================================================================
// ASYNC output-projection GEMM — R0-R5-proven 64x128 tile, BK=32, grid
// (64, 8) = 512 blocks = 2 blocks/CU (8 waves/CU). Reverted from the
// 128x128 1-block/CU version: session evidence (R3/R6/R7) shows duration
// tracks resident waves/CU; 1 wave/SIMD is latency-exposed.
// ===========================================================================
__global__ __launch_bounds__(256)
void out_gemm_async(const bf16* __restrict__ A, const unsigned short* __restrict__ Wt,
                    const unsigned short* __restrict__ bias, char* __restrict__ C,
                    const int* __restrict__ flagp) {
  constexpr int K = Dc, N = Dc;
  __shared__ __align__(16) unsigned short At[64 * 32];
  __shared__ __align__(16) unsigned short Bt[128 * 32];

  const int cf = flagp[0];
  const int tid = threadIdx.x;
  const int m0 = blockIdx.x * 64, n0 = blockIdx.y * 128;
  const int w = tid >> 6, lane = tid & 63;
  const int lo16 = lane & 15, quad = lane >> 4;
  const int wm = (w >> 1) * 32, wn = (w & 1) * 64;

  unsigned short* ldsA = &At[w * 512 + lane * 8];
  unsigned short* ldsB = &Bt[w * 1024 + lane * 8];
  const bf16* gA = A + (size_t)(m0 + w * 16 + (lane >> 2)) * K + (lane & 3) * 8;
  const unsigned short* gB = Wt + (size_t)(n0 + w * 32 + (lane >> 2)) * K + (lane & 3) * 8;

  f32x4 acc[2][4] = {};

  for (int k0 = 0; k0 < K; k0 += 32) {
    gld16(gA + k0, ldsA);
    gld16(gB + k0, ldsB);
    gld16(gB + (size_t)16 * K + k0, ldsB + 512);
    __syncthreads();

    bf16x8 afr[2], bfr[4];
#pragma unroll
    for (int mt = 0; mt < 2; ++mt)
      afr[mt] = *reinterpret_cast<const bf16x8*>(&At[(wm + mt * 16 + lo16) * 32 + quad * 8]);
#pragma unroll
    for (int nt = 0; nt < 4; ++nt)
      bfr[nt] = *reinterpret_cast<const bf16x8*>(&Bt[(wn + nt * 16 + lo16) * 32 + quad * 8]);
#pragma unroll
    for (int mt = 0; mt < 2; ++mt)
#pragma unroll
      for (int nt = 0; nt < 4; ++nt)
        acc[mt][nt] = __builtin_amdgcn_mfma_f32_16x16x32_bf16(afr[mt], bfr[nt],
                                                              acc[mt][nt], 0, 0, 0);
    __syncthreads();
  }

  float bv[4];
#pragma unroll
  for (int nt = 0; nt < 4; ++nt)
    bv[nt] = bfbits2f(bias[n0 + wn + nt * 16 + lo16]);
#pragma unroll
  for (int mt = 0; mt < 2; ++mt)
#pragma unroll
    for (int r = 0; r < 4; ++r) {
      const int row = m0 + wm + mt * 16 + quad * 4 + r;
#pragma unroll
      for (int nt = 0; nt < 4; ++nt) {
        const int col = n0 + wn + nt * 16 + lo16;
        store1_dyn(C, (size_t)row * N + col, cf, acc[mt][nt][r] + bv[nt]);
      }
    }
}

// ===========================================================================
// MFMA causal flash attention, R7 split-K schedule (proven, unchanged).
// ===========================================================================
template <int SPLIT>
__global__ __launch_bounds__(256, 2)
void attn_mfma(const bf16* __restrict__ Q, const bf16* __restrict__ K,
               const bf16* __restrict__ V, bf16* __restrict__ O,
               float* __restrict__ P, float* __restrict__ Lp) {
  __shared__ __align__(16) unsigned short Kt[64][72];      // [key][dk]
  __shared__ __align__(16) unsigned short Vt[64][72];      // [dk][key]
  __shared__ __align__(16) unsigned short St[4][32][72];   // per-wave P [q][key]
  __shared__ float Li[4][32];                              // per-wave 1/l

  const int hb = blockIdx.x & 31;
  int c, t0, t1, part;
  if constexpr (SPLIT) {
    const int u = blockIdx.x >> 5;   // 0..23
    if (u < 8)       { c = u;      t0 = 0;     t1 = 2 * c + 2; part = 0; }
    else if (u < 16) { c = 23 - u; t0 = 0;     t1 = c + 1;     part = 1; }
    else             { c = 31 - u; t0 = c + 1; t1 = 2 * c + 2; part = 2; }
  } else {
    const int i = blockIdx.x >> 5, g = i >> 3, r0 = i & 7;
    c = g ? (15 - r0) : r0; t0 = 0; t1 = 2 * (c + 1); part = 0;
  }
  const int b = hb >> 4, h = hb & 15;
  const int q0 = c * 128;
  const int tid = threadIdx.x;
  const int w = tid >> 6;                  // 0..3
  const int lane = tid & 63;
  const int lo16 = lane & 15, quad = lane >> 4;
  const size_t hd = (size_t)h * DKc;

  // staging patterns (256 threads, both roles per thread) — R3 verbatim
  const int kr = tid >> 2, kc = (tid & 3) * 16;         // K copy (2 x 16B)
  const int vk = (tid & 31) * 2, vd0 = (tid >> 5) * 8;  // V transpose

  // Q fragments for the wave's two 16-row groups
  const bf16* qrowA = Q + ((size_t)(b * Sc + q0 + w * 32 + lo16)) * Dc + hd;
  const bf16x8 qa0 = *reinterpret_cast<const bf16x8*>(qrowA + quad * 8);
  const bf16x8 qa1 = *reinterpret_cast<const bf16x8*>(qrowA + 32 + quad * 8);
  const bf16* qrowB = qrowA + (size_t)16 * Dc;
  const bf16x8 qb0 = *reinterpret_cast<const bf16x8*>(qrowB + quad * 8);
  const bf16x8 qb1 = *reinterpret_cast<const bf16x8*>(qrowB + 32 + quad * 8);

  f32x4 oA[4] = {f32x4{0,0,0,0}, f32x4{0,0,0,0}, f32x4{0,0,0,0}, f32x4{0,0,0,0}};
  f32x4 oB[4] = {f32x4{0,0,0,0}, f32x4{0,0,0,0}, f32x4{0,0,0,0}, f32x4{0,0,0,0}};
  float lsA = 0.f, lsB = 0.f;
  const int qgA = q0 + w * 32 + lo16;      // lane's q, group A
  const int qgB = qgA + 16;                // lane's q, group B
  const int qmaxA = q0 + w * 32 + 15;      // group A max q row
  const int qmaxB = qmaxA + 16;            // group B max q row

  const bf16* ksrc = K + ((size_t)(b * Sc + kr)) * Dc + hd + kc;
  const bf16* vsrc = V + ((size_t)(b * Sc + vk)) * Dc + hd + vd0;

  // ---- prologue: tile-t0 loads into registers ----
  const size_t off0 = (size_t)t0 * 64 * Dc;
  uint4 rKa = *reinterpret_cast<const uint4*>(ksrc + off0);
  uint4 rKb = *reinterpret_cast<const uint4*>(ksrc + off0 + 8);
  uint4 rVa = *reinterpret_cast<const uint4*>(vsrc + off0);
  uint4 rVb = *reinterpret_cast<const uint4*>(vsrc + off0 + Dc);

  for (int t = t0; t < t1; ++t) {
    const int kt = t * 64;
    __syncthreads();   // prior iter's frag reads complete
    // ---- commit staged registers to LDS ----
    *reinterpret_cast<uint4*>(&Kt[kr][kc])     = rKa;
    *reinterpret_cast<uint4*>(&Kt[kr][kc + 8]) = rKb;
    *reinterpret_cast<unsigned*>(&Vt[vd0 + 0][vk]) = (rVa.x & 0xffffu) | (rVb.x << 16);
    *reinterpret_cast<unsigned*>(&Vt[vd0 + 1][vk]) = (rVa.x >> 16)     | (rVb.x & 0xffff0000u);
    *reinterpret_cast<unsigned*>(&Vt[vd0 + 2][vk]) = (rVa.y & 0xffffu) | (rVb.y << 16);
    *reinterpret_cast<unsigned*>(&Vt[vd0 + 3][vk]) = (rVa.y >> 16)     | (rVb.y & 0xffff0000u);
    *reinterpret_cast<unsigned*>(&Vt[vd0 + 4][vk]) = (rVa.z & 0xffffu) | (rVb.z << 16);
    *reinterpret_cast<unsigned*>(&Vt[vd0 + 5][vk]) = (rVa.z >> 16)     | (rVb.z & 0xffff0000u);
    *reinterpret_cast<unsigned*>(&Vt[vd0 + 6][vk]) = (rVa.w & 0xffffu) | (rVb.w << 16);
    *reinterpret_cast<unsigned*>(&Vt[vd0 + 7][vk]) = (rVa.w >> 16)     | (rVb.w & 0xffff0000u);
    __syncthreads();

    // ---- T14: next tile's loads fly during compute ----
    if (t + 1 < t1) {
      const size_t off = (size_t)(t + 1) * 64 * Dc;
      rKa = *reinterpret_cast<const uint4*>(ksrc + off);
      rKb = *reinterpret_cast<const uint4*>(ksrc + off + 8);
      rVa = *reinterpret_cast<const uint4*>(vsrc + off);
      rVb = *reinterpret_cast<const uint4*>(vsrc + off + Dc);
    }

    if (kt > qmaxB) continue;   // whole wave masked (barriers already passed)
    const bool liveA = (kt <= qmaxA);

    // ---- K fragments from LDS, shared by both q-groups ----
    bf16x8 ka[4], kb[4];
#pragma unroll
    for (int ct = 0; ct < 4; ++ct) {
      ka[ct] = *reinterpret_cast<const bf16x8*>(&Kt[ct * 16 + lo16][quad * 8]);
      kb[ct] = *reinterpret_cast<const bf16x8*>(&Kt[ct * 16 + lo16][32 + quad * 8]);
    }

    // ---- S^T = K Q^T for both groups ----
    f32x4 sA[4] = {f32x4{0,0,0,0}, f32x4{0,0,0,0}, f32x4{0,0,0,0}, f32x4{0,0,0,0}};
    f32x4 sB[4] = {f32x4{0,0,0,0}, f32x4{0,0,0,0}, f32x4{0,0,0,0}, f32x4{0,0,0,0}};
    __builtin_amdgcn_s_setprio(1);
#pragma unroll
    for (int ct = 0; ct < 4; ++ct) {
      sB[ct] = __builtin_amdgcn_mfma_f32_16x16x32_bf16(ka[ct], qb0, sB[ct], 0, 0, 0);
      sB[ct] = __builtin_amdgcn_mfma_f32_16x16x32_bf16(kb[ct], qb1, sB[ct], 0, 0, 0);
    }
    if (liveA) {
#pragma unroll
      for (int ct = 0; ct < 4; ++ct) {
        sA[ct] = __builtin_amdgcn_mfma_f32_16x16x32_bf16(ka[ct], qa0, sA[ct], 0, 0, 0);
        sA[ct] = __builtin_amdgcn_mfma_f32_16x16x32_bf16(kb[ct], qa1, sA[ct], 0, 0, 0);
      }
    }
    __builtin_amdgcn_s_setprio(0);

    // ---- causal mask: only diagonal-adjacent tiles (wave-uniform tests) ----
    if (kt + 63 > q0 + w * 32 + 16) {   // group B
#pragma unroll
      for (int ct = 0; ct < 4; ++ct)
#pragma unroll
        for (int r = 0; r < 4; ++r)
          if (kt + ct * 16 + quad * 4 + r > qgB) sB[ct][r] = -1e9f;
    }
    if (liveA && (kt + 63 > q0 + w * 32)) {   // group A
#pragma unroll
      for (int ct = 0; ct < 4; ++ct)
#pragma unroll
        for (int r = 0; r < 4; ++r)
          if (kt + ct * 16 + quad * 4 + r > qgA) sA[ct][r] = -1e9f;
    }

    // ---- unnormalized softmax: p = exp2(s) ----
#pragma unroll
    for (int ct = 0; ct < 4; ++ct) {
      const float p0 = fast_exp2(sB[ct][0]);
      const float p1 = fast_exp2(sB[ct][1]);
      const float p2 = fast_exp2(sB[ct][2]);
      const float p3 = fast_exp2(sB[ct][3]);
      lsB += (p0 + p1) + (p2 + p3);
      uint2 pk;
      pk.x = pkbf16(p0, p1);
      pk.y = pkbf16(p2, p3);
      *reinterpret_cast<uint2*>(&St[w][16 + lo16][ct * 16 + quad * 4]) = pk;
    }
    if (liveA) {
#pragma unroll
      for (int ct = 0; ct < 4; ++ct) {
        const float p0 = fast_exp2(sA[ct][0]);
        const float p1 = fast_exp2(sA[ct][1]);
        const float p2 = fast_exp2(sA[ct][2]);
        const float p3 = fast_exp2(sA[ct][3]);
        lsA += (p0 + p1) + (p2 + p3);
        uint2 pk;
        pk.x = pkbf16(p0, p1);
        pk.y = pkbf16(p2, p3);
        *reinterpret_cast<uint2*>(&St[w][lo16][ct * 16 + quad * 4]) = pk;
      }
    }

    // ---- PV: V fragments shared by both groups ----
    const bf16x8 pb0 = *reinterpret_cast<const bf16x8*>(&St[w][16 + lo16][quad * 8]);
    const bf16x8 pb1 = *reinterpret_cast<const bf16x8*>(&St[w][16 + lo16][32 + quad * 8]);
    const bf16x8 pa0 = *reinterpret_cast<const bf16x8*>(&St[w][lo16][quad * 8]);
    const bf16x8 pa1 = *reinterpret_cast<const bf16x8*>(&St[w][lo16][32 + quad * 8]);
    __builtin_amdgcn_s_setprio(1);
#pragma unroll
    for (int ct = 0; ct < 4; ++ct) {
      const bf16x8 vb0 = *reinterpret_cast<const bf16x8*>(&Vt[ct * 16 + lo16][quad * 8]);
      const bf16x8 vb1 = *reinterpret_cast<const bf16x8*>(&Vt[ct * 16 + lo16][32 + quad * 8]);
      oB[ct] = __builtin_amdgcn_mfma_f32_16x16x32_bf16(pb0, vb0, oB[ct], 0, 0, 0);
      oB[ct] = __builtin_amdgcn_mfma_f32_16x16x32_bf16(pb1, vb1, oB[ct], 0, 0, 0);
      if (liveA) {
        oA[ct] = __builtin_amdgcn_mfma_f32_16x16x32_bf16(pa0, vb0, oA[ct], 0, 0, 0);
        oA[ct] = __builtin_amdgcn_mfma_f32_16x16x32_bf16(pa1, vb1, oA[ct], 0, 0, 0);
      }
    }
    __builtin_amdgcn_s_setprio(0);
  }

  // ---- per-group l reduction (butterfly: every lane gets its column's sum) ----
  lsA += __shfl_xor(lsA, 16);
  lsA += __shfl_xor(lsA, 32);
  lsB += __shfl_xor(lsB, 16);
  lsB += __shfl_xor(lsB, 32);

  if (SPLIT && part != 0) {
    // ---- partial epilogue: raw f32 O + l to workspace (merged later) ----
    float* Pp = P + ((size_t)(part - 1) * 32 + hb) * (size_t)(1024 * 64);
    float* Lq = Lp + ((size_t)(part - 1) * 32 + hb) * 1024;
    const int qlA = q0 - 1024 + w * 32;    // partial chunks have q0 >= 1024
    if (quad == 0) {
      Lq[qlA + lo16] = lsA;
      Lq[qlA + 16 + lo16] = lsB;
    }
#pragma unroll
    for (int r = 0; r < 4; ++r) {
      float* pA = Pp + (size_t)(qlA + quad * 4 + r) * 64 + lo16;
      float* pB = Pp + (size_t)(qlA + 16 + quad * 4 + r) * 64 + lo16;
#pragma unroll
      for (int ct = 0; ct < 4; ++ct) {
        pA[ct * 16] = oA[ct][r];
        pB[ct * 16] = oB[ct][r];
      }
    }
    return;
  }

  // ---- direct epilogue (R3 verbatim) ----
  if (quad == 0) {
    Li[w][lo16] = 1.f / lsA;
    Li[w][16 + lo16] = 1.f / lsB;
  }
  __builtin_amdgcn_wave_barrier();
  const f32x4 invA = *reinterpret_cast<const f32x4*>(&Li[w][quad * 4]);
  const f32x4 invB = *reinterpret_cast<const f32x4*>(&Li[w][16 + quad * 4]);

#pragma unroll
  for (int r = 0; r < 4; ++r) {
    bf16* opA = O + (((size_t)(b * Hc + h) * Sc) + q0 + w * 32 + quad * 4 + r) * DKc + lo16;
    bf16* opB = opA + (size_t)16 * DKc;
#pragma unroll
    for (int ct = 0; ct < 4; ++ct) {
      opA[ct * 16] = __float2bfloat16(oA[ct][r] * invA[r]);
      opB[ct * 16] = __float2bfloat16(oB[ct][r] * invB[r]);
    }
  }
}

// ===========================================================================
// Merge the two k-half partials for chunks 8..15 (q in [1024,2048)):
// att[hb][1024+q][d] = (P0 + P1) / (l0 + l1). 2048 blocks x 256 thr x 4 elems.
// ===========================================================================
__global__ __launch_bounds__(256)
void merge_att(const float* __restrict__ P, const float* __restrict__ Lp,
               bf16* __restrict__ att) {
  const int e = blockIdx.x * 256 + threadIdx.x;   // 0 .. 524287
  const int d4 = (e & 15) * 4;
  const int q  = (e >> 4) & 1023;
  const int hb = e >> 14;                         // 0..31
  const size_t pi = ((size_t)hb * 1024 + q) * 64 + d4;
  const float4 a = *reinterpret_cast<const float4*>(P + pi);
  const float4 c = *reinterpret_cast<const float4*>(P + (size_t)2097152 + pi);
  const float inv = 1.f / (Lp[hb * 1024 + q] + Lp[32768 + hb * 1024 + q]);
  uint2 o;
  o.x = pkbf16((a.x + c.x) * inv, (a.y + c.y) * inv);
  o.y = pkbf16((a.z + c.z) * inv, (a.w + c.w) * inv);
  *reinterpret_cast<uint2*>(att + ((size_t)hb * 2048 + 1024 + q) * 64 + d4) = o;
}

// ===========================================================================
extern "C" void kernel_launch(void* const* d_in, const int* in_sizes, int n_in,
                              void* d_out, int out_size, void* d_ws, size_t ws_size,
                              hipStream_t stream) {
  (void)in_sizes; (void)out_size;
  const char* query = (const char*)d_in[0];
  const char* key_  = (const char*)d_in[1];
  const char* value = (const char*)d_in[2];
  const int wb = n_in - 8;   // weights/biases are the last 8 inputs
  const char* Wq = (const char*)d_in[wb + 0];
  const char* bq = (const char*)d_in[wb + 1];
  const char* Wk = (const char*)d_in[wb + 2];
  const char* bk = (const char*)d_in[wb + 3];
  const char* Wv = (const char*)d_in[wb + 4];
  const char* bv = (const char*)d_in[wb + 5];
  const char* Wo = (const char*)d_in[wb + 6];
  const char* bo = (const char*)d_in[wb + 7];

  char* ws = (char*)d_ws;
  bf16* Qs  = (bf16*)(ws);                         // 8 MiB
  bf16* Ks  = (bf16*)(ws + ((size_t)8  << 20));    // 8 MiB
  bf16* Vs  = (bf16*)(ws + ((size_t)16 << 20));    // 8 MiB
  bf16* att = (bf16*)(ws + ((size_t)24 << 20));    // 8 MiB
  unsigned short* Wt_all = (unsigned short*)(ws + ((size_t)32 << 20));  // 4 x 2 MiB
  unsigned short* bb_all = (unsigned short*)(ws + ((size_t)40 << 20));  // 8 KiB
  int* flag = (int*)(ws + ((size_t)40 << 20) + 16384);
  bf16* Qb = (bf16*)(ws + ((size_t)42 << 20));     // 8 MiB (converted inputs)
  bf16* Kb = (bf16*)(ws + ((size_t)50 << 20));
  bf16* Vb = (bf16*)(ws + ((size_t)58 << 20));
  // attn split-K partials overlay the (dead-after-qkv) Qb/Kb/Vb region:
  float* Pw = (float*)(ws + ((size_t)42 << 20));   // 2 x 8.39 MiB f32 (42..58.8M)
  float* Lw = (float*)(ws + ((size_t)59 << 20));   // 2 x 128 KiB f32
  const bool big_ws = ws_size >= ((size_t)66 << 20);

  if (big_ws) {
    prep_all<<<2564, 256, 0, stream>>>(Wq, Wk, Wv, Wo, Wt_all, bq, bk, bv, bo,
                                       bb_all, query, key_, value, Qb, Kb, Vb, flag);
    qkv_gemm_async<<<dim3(32, 8, 3), 256, 0, stream>>>(Qb, Kb, Vb, Wt_all, bb_all,
                                                       Qs, Ks, Vs);
    attn_mfma<1><<<dim3(768), 256, 0, stream>>>(Qs, Ks, Vs, att, Pw, Lw);
    merge_att<<<dim3(2048), 256, 0, stream>>>(Pw, Lw, att);
  } else {
    // fallback: grid 1028 covers transpose (0..1023) + bias/flag (1024..1027)
    prep_all<<<1028, 256, 0, stream>>>(Wq, Wk, Wv, Wo, Wt_all, bq, bk, bv, bo,
                                       bb_all, query, key_, value,
                                       (bf16*)att, (bf16*)att, (bf16*)att, flag);
    qkv_gemm<<<dim3(32, 8, 3), 256, 0, stream>>>(query, key_, value, Wt_all, bb_all,
                                                 Qs, Ks, Vs, flag);
    attn_mfma<0><<<dim3(512), 256, 0, stream>>>(Qs, Ks, Vs, att, Pw, Lw);
  }

  out_gemm_async<<<dim3(64, 8), 256, 0, stream>>>(att, Wt_all + (size_t)3 * Dc * Dc,
                                                  bb_all + 3 * Dc, (char*)d_out, flag);
}

// Round 11
// 221.075 us; speedup vs baseline: 1.2503x; 1.0341x over previous
//
#include <hip/hip_runtime.h>
#include <hip/hip_bf16.h>

typedef __hip_bfloat16 bf16;
typedef __attribute__((ext_vector_type(8))) short bf16x8;  // 8 bf16 (4 VGPRs)
typedef __attribute__((ext_vector_type(4))) float f32x4;

constexpr int Bc  = 2;
constexpr int Sc  = 2048;
constexpr int Dc  = 1024;   // = H * DK
constexpr int Hc  = 16;
constexpr int DKc = 64;

__device__ __forceinline__ float bfbits2f(unsigned short u) {
  return __uint_as_float(((unsigned)u) << 16);
}
__device__ __forceinline__ unsigned short f2bfbits(float x) {
  bf16 h = __float2bfloat16(x);
  return *reinterpret_cast<unsigned short*>(&h);
}
__device__ __forceinline__ void store1_dyn(char* base, size_t ei, int isf32, float v) {
  if (isf32) *reinterpret_cast<float*>(base + ei * 4) = v;
  else       *reinterpret_cast<bf16*>(base + ei * 2) = __float2bfloat16(v);
}
__device__ __forceinline__ float fast_exp2(float x) {
  return __builtin_amdgcn_exp2f(x);
}
// packed pair f32->bf16 (v_cvt_pk_bf16_f32)
__device__ __forceinline__ unsigned pkbf16(float a, float b) {
  __hip_bfloat162 h = __float22bfloat162_rn(make_float2(a, b));
  return *reinterpret_cast<unsigned*>(&h);
}
// pack 8 floats (two float4) -> uint4 of 8 bf16 (memory order preserved)
__device__ __forceinline__ uint4 pack8(const float4& a, const float4& b) {
  uint4 r;
  r.x = pkbf16(a.x, a.y);
  r.y = pkbf16(a.z, a.w);
  r.z = pkbf16(b.x, b.y);
  r.w = pkbf16(b.z, b.w);
  return r;
}
// async global->LDS direct copy, 16 B per lane (gfx950)
__device__ __forceinline__ void gld16(const void* g, void* l) {
  __builtin_amdgcn_global_load_lds(
      (const __attribute__((address_space(1))) unsigned int*)g,
      (__attribute__((address_space(3))) unsigned int*)l, 16, 0, 0);
}

// ===========================================================================
// Fused prep (R7-proven): detect folded in; every block votes locally.
//   id in [0,1024)     : transpose+bf16-ify the 4 weight matrices
//   id in [1024,1028)  : convert the 4 bias vectors (block 1024 writes flag)
//   id in [1028,2564)  : convert q/k/v inputs to bf16
// Fallback grid 1028 covers transpose + bias (and flag).
// ===========================================================================
__global__ __launch_bounds__(256)
void prep_all(const char* __restrict__ W0, const char* __restrict__ W1,
              const char* __restrict__ W2, const char* __restrict__ W3,
              unsigned short* __restrict__ Wt_all,
              const char* __restrict__ b0, const char* __restrict__ b1,
              const char* __restrict__ b2, const char* __restrict__ b3,
              unsigned short* __restrict__ bb_all,
              const char* __restrict__ A0, const char* __restrict__ A1,
              const char* __restrict__ A2, bf16* __restrict__ B0,
              bf16* __restrict__ B1, bf16* __restrict__ B2,
              int* __restrict__ flag_out) {
  __shared__ unsigned short T[64][72];
  __shared__ int cnt[256];
  const int id = blockIdx.x;
  const int tid = threadIdx.x;

  // ---- inline dtype detection (deterministic, identical in every block) ----
  {
    const unsigned short* q = reinterpret_cast<const unsigned short*>(A0);
    int c = 0;
    for (int i = tid; i < 2048; i += 256) {
      const unsigned short u = q[i];
      const int e = (u >> 7) & 0xFF;
      if (e >= 134 || e <= 90) ++c;
    }
    cnt[tid] = c;
    __syncthreads();
    for (int s = 128; s > 0; s >>= 1) {
      if (tid < s) cnt[tid] += cnt[tid + s];
      __syncthreads();
    }
  }
  const int dyn = (cnt[0] > 64) ? 1 : 0;

  if (id < 1024) {
    // ---- weight transpose ----
    const int z = id >> 8, rem = id & 255;
    const int n0 = (rem & 15) * 64, k0 = (rem >> 4) * 64;
    const char* W = (z == 0) ? W0 : (z == 1) ? W1 : (z == 2) ? W2 : W3;
    unsigned short* Wt = Wt_all + (size_t)z * Dc * Dc;
    const int r = tid >> 2, c16 = (tid & 3) * 16;

    unsigned short us[16];
    if (dyn) {
      const float4* p = reinterpret_cast<const float4*>(
          W + ((size_t)(k0 + r) * Dc + n0 + c16) * 4);
      const float4 f0 = p[0], f1 = p[1], f2 = p[2], f3 = p[3];
      const float fv[16] = {f0.x, f0.y, f0.z, f0.w, f1.x, f1.y, f1.z, f1.w,
                            f2.x, f2.y, f2.z, f2.w, f3.x, f3.y, f3.z, f3.w};
#pragma unroll
      for (int i = 0; i < 16; ++i) us[i] = f2bfbits(fv[i]);
    } else {
      const ushort4* p = reinterpret_cast<const ushort4*>(
          W + ((size_t)(k0 + r) * Dc + n0 + c16) * 2);
      const ushort4 u0 = p[0], u1 = p[1], u2 = p[2], u3 = p[3];
      us[0] = u0.x;  us[1] = u0.y;  us[2] = u0.z;  us[3] = u0.w;
      us[4] = u1.x;  us[5] = u1.y;  us[6] = u1.z;  us[7] = u1.w;
      us[8] = u2.x;  us[9] = u2.y;  us[10] = u2.z; us[11] = u2.w;
      us[12] = u3.x; us[13] = u3.y; us[14] = u3.z; us[15] = u3.w;
    }
#pragma unroll
    for (int i = 0; i < 16; ++i) T[r][c16 + i] = us[i];
    __syncthreads();

    unsigned vs[8];
#pragma unroll
    for (int i = 0; i < 8; ++i)
      vs[i] = (unsigned)T[c16 + 2 * i][r] | ((unsigned)T[c16 + 2 * i + 1][r] << 16);
    uint4* op = reinterpret_cast<uint4*>(Wt + (size_t)(n0 + r) * Dc + k0 + c16);
    op[0] = make_uint4(vs[0], vs[1], vs[2], vs[3]);
    op[1] = make_uint4(vs[4], vs[5], vs[6], vs[7]);
  } else if (id < 1028) {
    // ---- bias convert (+ flag publish for later dispatches) ----
    const int x = id - 1024;
    if (x == 0 && tid == 0) flag_out[0] = dyn;
    const char* src = (x == 0) ? b0 : (x == 1) ? b1 : (x == 2) ? b2 : b3;
    for (int i = tid; i < Dc; i += 256) {
      float v = dyn ? reinterpret_cast<const float*>(src)[i]
                    : bfbits2f(reinterpret_cast<const unsigned short*>(src)[i]);
      bb_all[x * Dc + i] = f2bfbits(v);
    }
  } else {
    // ---- q/k/v convert ----
    const int j = id - 1028;
    const int z = j >> 9, x = j & 511;
    const char* src = (z == 0) ? A0 : (z == 1) ? A1 : A2;
    bf16* dst = (z == 0) ? B0 : (z == 1) ? B1 : B2;
    const size_t n = (size_t)4096 * Dc;
    const size_t stride = (size_t)512 * 256 * 8;
    for (size_t i = ((size_t)x * 256 + tid) * 8; i < n; i += stride) {
      uint4 u;
      if (dyn) {
        const float4* p = reinterpret_cast<const float4*>(src + i * 4);
        u = pack8(p[0], p[1]);
      } else {
        u = *reinterpret_cast<const uint4*>(src + i * 2);
      }
      *reinterpret_cast<uint4*>(dst + i) = u;
    }
  }
}

// ===========================================================================
// ASYNC fused QKV MFMA GEMM, R11: 128x64 tile for OCCUPANCY.
// Evidence: qkv is latency-bound (HBM 19%, MFMA 22%, Occ 14%; 4x above both
// roofline floors), and R8 showed intra-block changes are neutral while R7
// showed resident-wave count is the lever. 128x64 tile -> grid (32,16,3) =
// 1536 blocks = 6 blocks/CU (LDS 24KB x 6 = 144 <= 160KB), doubling resident
// waves. Staging = R8-proven linear-LDS + pre-swizzled-source scheme:
//   A: verbatim R8 (wave w rows w*32+r*8+(lane>>3), 4 gld16).
//   B: rows n0 + r*32 + w*8 + (lane>>3) (r=0,1; row-group base multiple of 8
//      so the (row&7) XOR read is unchanged), 2 gld16.
// Read col XORs ((lo16&7)<<3); acc 4x2; BK=64, 0 bank conflicts.
// ===========================================================================
__global__ __launch_bounds__(256)
void qkv_gemm_async(const bf16* __restrict__ A0, const bf16* __restrict__ A1,
                    const bf16* __restrict__ A2,
                    const unsigned short* __restrict__ Wt_all,
                    const unsigned short* __restrict__ bias_all,
                    bf16* __restrict__ C0, bf16* __restrict__ C1,
                    bf16* __restrict__ C2) {
  constexpr int K = Dc, N = Dc;
  __shared__ __align__(16) unsigned short At[128 * 64];
  __shared__ __align__(16) unsigned short Bt[64 * 64];

  const int z = blockIdx.z;
  const bf16* A = (z == 0) ? A0 : (z == 1) ? A1 : A2;
  bf16* C = (z == 0) ? C0 : (z == 1) ? C1 : C2;
  const float scale = (z == 0) ? 0.18033688011112042f : 1.0f;  // qscale*log2e
  const unsigned short* Wt = Wt_all + (size_t)z * Dc * Dc;
  const unsigned short* bias = bias_all + z * Dc;

  const int tid = threadIdx.x;
  const int m0 = blockIdx.x * 128, n0 = blockIdx.y * 64;
  const int w = tid >> 6, lane = tid & 63;
  const int lo16 = lane & 15, quad = lane >> 4;
  const int wm = (w >> 1) * 64, wn = (w & 1) * 32;

  // linear LDS dest (wave-uniform base + lane*16B), pre-swizzled global col
  unsigned short* ldsA = &At[w * 2048 + lane * 8];
  const int ssw = ((lane & 7) ^ (lane >> 3)) * 8;      // source col swizzle
  const bf16* gA = A + (size_t)(m0 + w * 32 + (lane >> 3)) * K + ssw;
  // B: instr r covers rows n0 + r*32 + w*8 + (lane>>3)
  const unsigned short* gB = Wt + (size_t)(n0 + w * 8 + (lane >> 3)) * K + ssw;

  // read-side swizzle (row&7 == lo16&7 for all fragment rows)
  const int rsw = (lo16 & 7) << 3;
  const int c0 = (quad * 8) ^ rsw;          // kk=0 col (elements)
  const int c1 = (32 + quad * 8) ^ rsw;     // kk=1 col

  f32x4 acc[4][2] = {};

  for (int k0 = 0; k0 < K; k0 += 64) {
#pragma unroll
    for (int r = 0; r < 4; ++r)
      gld16(gA + (size_t)(r * 8) * K + k0, ldsA + r * 512);
#pragma unroll
    for (int r = 0; r < 2; ++r)
      gld16(gB + (size_t)(r * 32) * K + k0, &Bt[(r * 32 + w * 8) * 64 + lane * 8]);
    __syncthreads();   // drains vmcnt -> LDS tile ready

#pragma unroll
    for (int kk = 0; kk < 2; ++kk) {
      const int cc = kk ? c1 : c0;
      bf16x8 afr[4], bfr[2];
#pragma unroll
      for (int mt = 0; mt < 4; ++mt)
        afr[mt] = *reinterpret_cast<const bf16x8*>(&At[(wm + mt * 16 + lo16) * 64 + cc]);
#pragma unroll
      for (int nt = 0; nt < 2; ++nt)
        bfr[nt] = *reinterpret_cast<const bf16x8*>(&Bt[(wn + nt * 16 + lo16) * 64 + cc]);
#pragma unroll
      for (int mt = 0; mt < 4; ++mt)
#pragma unroll
        for (int nt = 0; nt < 2; ++nt)
          acc[mt][nt] = __builtin_amdgcn_mfma_f32_16x16x32_bf16(afr[mt], bfr[nt],
                                                                acc[mt][nt], 0, 0, 0);
    }
    __syncthreads();   // frag reads done before next iter's gld overwrite
  }

  float bv[2];
#pragma unroll
  for (int nt = 0; nt < 2; ++nt)
    bv[nt] = bfbits2f(bias[n0 + wn + nt * 16 + lo16]);
#pragma unroll
  for (int mt = 0; mt < 4; ++mt)
#pragma unroll
    for (int r = 0; r < 4; ++r) {
      const int row = m0 + wm + mt * 16 + quad * 4 + r;
#pragma unroll
      for (int nt = 0; nt < 2; ++nt) {
        const int col = n0 + wn + nt * 16 + lo16;
        C[(size_t)row * N + col] = __float2bfloat16((acc[mt][nt][r] + bv[nt]) * scale);
      }
    }
}

// ===========================================================================
// LEGACY fused QKV GEMM (VGPR staging, dynamic dtype) — ws-too-small fallback.
// ===========================================================================
__global__ __launch_bounds__(256)
void qkv_gemm(const char* __restrict__ A0, const char* __restrict__ A1,
              const char* __restrict__ A2, const unsigned short* __restrict__ Wt_all,
              const unsigned short* __restrict__ bias_all,
              bf16* __restrict__ C0, bf16* __restrict__ C1, bf16* __restrict__ C2,
              const int* __restrict__ flagp) {
  constexpr int K = Dc, N = Dc;
  __shared__ __align__(16) unsigned short At[128][32];
  __shared__ __align__(16) unsigned short Bt[128][32];

  const int z = blockIdx.z;
  const char* A = (z == 0) ? A0 : (z == 1) ? A1 : A2;
  bf16* C = (z == 0) ? C0 : (z == 1) ? C1 : C2;
  const float scale = (z == 0) ? 0.18033688011112042f : 1.0f;
  const unsigned short* Wt = Wt_all + (size_t)z * Dc * Dc;
  const unsigned short* bias = bias_all + z * Dc;
  const int af = flagp[0];

  const int tid = threadIdx.x;
  const int m0 = blockIdx.x * 128, n0 = blockIdx.y * 128;
  const int w = tid >> 6, lane = tid & 63;
  const int lo16 = lane & 15, quad = lane >> 4;
  const int wm = (w >> 1) * 64, wn = (w & 1) * 64;
  const int sr = tid >> 1, sh = (tid & 1) * 16;

  f32x4 acc[4][4] = {};

  for (int k0 = 0; k0 < K; k0 += 32) {
    uint4 a_lo, a_hi;
    if (af) {
      const float4* p = reinterpret_cast<const float4*>(
          A + ((size_t)(m0 + sr) * K + k0 + sh) * 4);
      a_lo = pack8(p[0], p[1]);
      a_hi = pack8(p[2], p[3]);
    } else {
      const uint4* p = reinterpret_cast<const uint4*>(
          A + ((size_t)(m0 + sr) * K + k0 + sh) * 2);
      a_lo = p[0];
      a_hi = p[1];
    }
    const uint4* wp = reinterpret_cast<const uint4*>(Wt + (size_t)(n0 + sr) * K + k0 + sh);
    const uint4 b_lo = wp[0], b_hi = wp[1];

    __syncthreads();
    *reinterpret_cast<uint4*>(&At[sr][sh])     = a_lo;
    *reinterpret_cast<uint4*>(&At[sr][sh + 8]) = a_hi;
    *reinterpret_cast<uint4*>(&Bt[sr][sh])     = b_lo;
    *reinterpret_cast<uint4*>(&Bt[sr][sh + 8]) = b_hi;
    __syncthreads();

    bf16x8 afr[4], bfr[4];
#pragma unroll
    for (int mt = 0; mt < 4; ++mt)
      afr[mt] = *reinterpret_cast<const bf16x8*>(&At[wm + mt * 16 + lo16][quad * 8]);
#pragma unroll
    for (int nt = 0; nt < 4; ++nt)
      bfr[nt] = *reinterpret_cast<const bf16x8*>(&Bt[wn + nt * 16 + lo16][quad * 8]);
#pragma unroll
    for (int mt = 0; mt < 4; ++mt)
#pragma unroll
      for (int nt = 0; nt < 4; ++nt)
        acc[mt][nt] = __builtin_amdgcn_mfma_f32_16x16x32_bf16(afr[mt], bfr[nt],
                                                              acc[mt][nt], 0, 0, 0);
  }

  float bv[4];
#pragma unroll
  for (int nt = 0; nt < 4; ++nt)
    bv[nt] = bfbits2f(bias[n0 + wn + nt * 16 + lo16]);
#pragma unroll
  for (int mt = 0; mt < 4; ++mt)
#pragma unroll
    for (int r = 0; r < 4; ++r) {
      const int row = m0 + wm + mt * 16 + quad * 4 + r;
#pragma unroll
      for (int nt = 0; nt < 4; ++nt) {
        const int col = n0 + wn + nt * 16 + lo16;
        C[(size_t)row * N + col] = __float2bfloat16((acc[mt][nt][r] + bv[nt]) * scale);
      }
    }
}

// ===========================================================================
// ASYNC output-projection GEMM — 64x128 tile, BK=32, grid (64, 8) =
// 512 blocks = 2 blocks/CU (R10 config, passed).
// ===========================================================================
__global__ __launch_bounds__(256)
void out_gemm_async(const bf16* __restrict__ A, const unsigned short* __restrict__ Wt,
                    const unsigned short* __restrict__ bias, char* __restrict__ C,
                    const int* __restrict__ flagp) {
  constexpr int K = Dc, N = Dc;
  __shared__ __align__(16) unsigned short At[64 * 32];
  __shared__ __align__(16) unsigned short Bt[128 * 32];

  const int cf = flagp[0];
  const int tid = threadIdx.x;
  const int m0 = blockIdx.x * 64, n0 = blockIdx.y * 128;
  const int w = tid >> 6, lane = tid & 63;
  const int lo16 = lane & 15, quad = lane >> 4;
  const int wm = (w >> 1) * 32, wn = (w & 1) * 64;

  unsigned short* ldsA = &At[w * 512 + lane * 8];
  unsigned short* ldsB = &Bt[w * 1024 + lane * 8];
  const bf16* gA = A + (size_t)(m0 + w * 16 + (lane >> 2)) * K + (lane & 3) * 8;
  const unsigned short* gB = Wt + (size_t)(n0 + w * 32 + (lane >> 2)) * K + (lane & 3) * 8;

  f32x4 acc[2][4] = {};

  for (int k0 = 0; k0 < K; k0 += 32) {
    gld16(gA + k0, ldsA);
    gld16(gB + k0, ldsB);
    gld16(gB + (size_t)16 * K + k0, ldsB + 512);
    __syncthreads();

    bf16x8 afr[2], bfr[4];
#pragma unroll
    for (int mt = 0; mt < 2; ++mt)
      afr[mt] = *reinterpret_cast<const bf16x8*>(&At[(wm + mt * 16 + lo16) * 32 + quad * 8]);
#pragma unroll
    for (int nt = 0; nt < 4; ++nt)
      bfr[nt] = *reinterpret_cast<const bf16x8*>(&Bt[(wn + nt * 16 + lo16) * 32 + quad * 8]);
#pragma unroll
    for (int mt = 0; mt < 2; ++mt)
#pragma unroll
      for (int nt = 0; nt < 4; ++nt)
        acc[mt][nt] = __builtin_amdgcn_mfma_f32_16x16x32_bf16(afr[mt], bfr[nt],
                                                              acc[mt][nt], 0, 0, 0);
    __syncthreads();
  }

  float bv[4];
#pragma unroll
  for (int nt = 0; nt < 4; ++nt)
    bv[nt] = bfbits2f(bias[n0 + wn + nt * 16 + lo16]);
#pragma unroll
  for (int mt = 0; mt < 2; ++mt)
#pragma unroll
    for (int r = 0; r < 4; ++r) {
      const int row = m0 + wm + mt * 16 + quad * 4 + r;
#pragma unroll
      for (int nt = 0; nt < 4; ++nt) {
        const int col = n0 + wn + nt * 16 + lo16;
        store1_dyn(C, (size_t)row * N + col, cf, acc[mt][nt][r] + bv[nt]);
      }
    }
}

// ===========================================================================
// MFMA causal flash attention, R7 split-K schedule (proven, unchanged).
// ===========================================================================
template <int SPLIT>
__global__ __launch_bounds__(256, 2)
void attn_mfma(const bf16* __restrict__ Q, const bf16* __restrict__ K,
               const bf16* __restrict__ V, bf16* __restrict__ O,
               float* __restrict__ P, float* __restrict__ Lp) {
  __shared__ __align__(16) unsigned short Kt[64][72];      // [key][dk]
  __shared__ __align__(16) unsigned short Vt[64][72];      // [dk][key]
  __shared__ __align__(16) unsigned short St[4][32][72];   // per-wave P [q][key]
  __shared__ float Li[4][32];                              // per-wave 1/l

  const int hb = blockIdx.x & 31;
  int c, t0, t1, part;
  if constexpr (SPLIT) {
    const int u = blockIdx.x >> 5;   // 0..23
    if (u < 8)       { c = u;      t0 = 0;     t1 = 2 * c + 2; part = 0; }
    else if (u < 16) { c = 23 - u; t0 = 0;     t1 = c + 1;     part = 1; }
    else             { c = 31 - u; t0 = c + 1; t1 = 2 * c + 2; part = 2; }
  } else {
    const int i = blockIdx.x >> 5, g = i >> 3, r0 = i & 7;
    c = g ? (15 - r0) : r0; t0 = 0; t1 = 2 * (c + 1); part = 0;
  }
  const int b = hb >> 4, h = hb & 15;
  const int q0 = c * 128;
  const int tid = threadIdx.x;
  const int w = tid >> 6;                  // 0..3
  const int lane = tid & 63;
  const int lo16 = lane & 15, quad = lane >> 4;
  const size_t hd = (size_t)h * DKc;

  // staging patterns (256 threads, both roles per thread) — R3 verbatim
  const int kr = tid >> 2, kc = (tid & 3) * 16;         // K copy (2 x 16B)
  const int vk = (tid & 31) * 2, vd0 = (tid >> 5) * 8;  // V transpose

  // Q fragments for the wave's two 16-row groups
  const bf16* qrowA = Q + ((size_t)(b * Sc + q0 + w * 32 + lo16)) * Dc + hd;
  const bf16x8 qa0 = *reinterpret_cast<const bf16x8*>(qrowA + quad * 8);
  const bf16x8 qa1 = *reinterpret_cast<const bf16x8*>(qrowA + 32 + quad * 8);
  const bf16* qrowB = qrowA + (size_t)16 * Dc;
  const bf16x8 qb0 = *reinterpret_cast<const bf16x8*>(qrowB + quad * 8);
  const bf16x8 qb1 = *reinterpret_cast<const bf16x8*>(qrowB + 32 + quad * 8);

  f32x4 oA[4] = {f32x4{0,0,0,0}, f32x4{0,0,0,0}, f32x4{0,0,0,0}, f32x4{0,0,0,0}};
  f32x4 oB[4] = {f32x4{0,0,0,0}, f32x4{0,0,0,0}, f32x4{0,0,0,0}, f32x4{0,0,0,0}};
  float lsA = 0.f, lsB = 0.f;
  const int qgA = q0 + w * 32 + lo16;      // lane's q, group A
  const int qgB = qgA + 16;                // lane's q, group B
  const int qmaxA = q0 + w * 32 + 15;      // group A max q row
  const int qmaxB = qmaxA + 16;            // group B max q row

  const bf16* ksrc = K + ((size_t)(b * Sc + kr)) * Dc + hd + kc;
  const bf16* vsrc = V + ((size_t)(b * Sc + vk)) * Dc + hd + vd0;

  // ---- prologue: tile-t0 loads into registers ----
  const size_t off0 = (size_t)t0 * 64 * Dc;
  uint4 rKa = *reinterpret_cast<const uint4*>(ksrc + off0);
  uint4 rKb = *reinterpret_cast<const uint4*>(ksrc + off0 + 8);
  uint4 rVa = *reinterpret_cast<const uint4*>(vsrc + off0);
  uint4 rVb = *reinterpret_cast<const uint4*>(vsrc + off0 + Dc);

  for (int t = t0; t < t1; ++t) {
    const int kt = t * 64;
    __syncthreads();   // prior iter's frag reads complete
    // ---- commit staged registers to LDS ----
    *reinterpret_cast<uint4*>(&Kt[kr][kc])     = rKa;
    *reinterpret_cast<uint4*>(&Kt[kr][kc + 8]) = rKb;
    *reinterpret_cast<unsigned*>(&Vt[vd0 + 0][vk]) = (rVa.x & 0xffffu) | (rVb.x << 16);
    *reinterpret_cast<unsigned*>(&Vt[vd0 + 1][vk]) = (rVa.x >> 16)     | (rVb.x & 0xffff0000u);
    *reinterpret_cast<unsigned*>(&Vt[vd0 + 2][vk]) = (rVa.y & 0xffffu) | (rVb.y << 16);
    *reinterpret_cast<unsigned*>(&Vt[vd0 + 3][vk]) = (rVa.y >> 16)     | (rVb.y & 0xffff0000u);
    *reinterpret_cast<unsigned*>(&Vt[vd0 + 4][vk]) = (rVa.z & 0xffffu) | (rVb.z << 16);
    *reinterpret_cast<unsigned*>(&Vt[vd0 + 5][vk]) = (rVa.z >> 16)     | (rVb.z & 0xffff0000u);
    *reinterpret_cast<unsigned*>(&Vt[vd0 + 6][vk]) = (rVa.w & 0xffffu) | (rVb.w << 16);
    *reinterpret_cast<unsigned*>(&Vt[vd0 + 7][vk]) = (rVa.w >> 16)     | (rVb.w & 0xffff0000u);
    __syncthreads();

    // ---- T14: next tile's loads fly during compute ----
    if (t + 1 < t1) {
      const size_t off = (size_t)(t + 1) * 64 * Dc;
      rKa = *reinterpret_cast<const uint4*>(ksrc + off);
      rKb = *reinterpret_cast<const uint4*>(ksrc + off + 8);
      rVa = *reinterpret_cast<const uint4*>(vsrc + off);
      rVb = *reinterpret_cast<const uint4*>(vsrc + off + Dc);
    }

    if (kt > qmaxB) continue;   // whole wave masked (barriers already passed)
    const bool liveA = (kt <= qmaxA);

    // ---- K fragments from LDS, shared by both q-groups ----
    bf16x8 ka[4], kb[4];
#pragma unroll
    for (int ct = 0; ct < 4; ++ct) {
      ka[ct] = *reinterpret_cast<const bf16x8*>(&Kt[ct * 16 + lo16][quad * 8]);
      kb[ct] = *reinterpret_cast<const bf16x8*>(&Kt[ct * 16 + lo16][32 + quad * 8]);
    }

    // ---- S^T = K Q^T for both groups ----
    f32x4 sA[4] = {f32x4{0,0,0,0}, f32x4{0,0,0,0}, f32x4{0,0,0,0}, f32x4{0,0,0,0}};
    f32x4 sB[4] = {f32x4{0,0,0,0}, f32x4{0,0,0,0}, f32x4{0,0,0,0}, f32x4{0,0,0,0}};
    __builtin_amdgcn_s_setprio(1);
#pragma unroll
    for (int ct = 0; ct < 4; ++ct) {
      sB[ct] = __builtin_amdgcn_mfma_f32_16x16x32_bf16(ka[ct], qb0, sB[ct], 0, 0, 0);
      sB[ct] = __builtin_amdgcn_mfma_f32_16x16x32_bf16(kb[ct], qb1, sB[ct], 0, 0, 0);
    }
    if (liveA) {
#pragma unroll
      for (int ct = 0; ct < 4; ++ct) {
        sA[ct] = __builtin_amdgcn_mfma_f32_16x16x32_bf16(ka[ct], qa0, sA[ct], 0, 0, 0);
        sA[ct] = __builtin_amdgcn_mfma_f32_16x16x32_bf16(kb[ct], qa1, sA[ct], 0, 0, 0);
      }
    }
    __builtin_amdgcn_s_setprio(0);

    // ---- causal mask: only diagonal-adjacent tiles (wave-uniform tests) ----
    if (kt + 63 > q0 + w * 32 + 16) {   // group B
#pragma unroll
      for (int ct = 0; ct < 4; ++ct)
#pragma unroll
        for (int r = 0; r < 4; ++r)
          if (kt + ct * 16 + quad * 4 + r > qgB) sB[ct][r] = -1e9f;
    }
    if (liveA && (kt + 63 > q0 + w * 32)) {   // group A
#pragma unroll
      for (int ct = 0; ct < 4; ++ct)
#pragma unroll
        for (int r = 0; r < 4; ++r)
          if (kt + ct * 16 + quad * 4 + r > qgA) sA[ct][r] = -1e9f;
    }

    // ---- unnormalized softmax: p = exp2(s) ----
#pragma unroll
    for (int ct = 0; ct < 4; ++ct) {
      const float p0 = fast_exp2(sB[ct][0]);
      const float p1 = fast_exp2(sB[ct][1]);
      const float p2 = fast_exp2(sB[ct][2]);
      const float p3 = fast_exp2(sB[ct][3]);
      lsB += (p0 + p1) + (p2 + p3);
      uint2 pk;
      pk.x = pkbf16(p0, p1);
      pk.y = pkbf16(p2, p3);
      *reinterpret_cast<uint2*>(&St[w][16 + lo16][ct * 16 + quad * 4]) = pk;
    }
    if (liveA) {
#pragma unroll
      for (int ct = 0; ct < 4; ++ct) {
        const float p0 = fast_exp2(sA[ct][0]);
        const float p1 = fast_exp2(sA[ct][1]);
        const float p2 = fast_exp2(sA[ct][2]);
        const float p3 = fast_exp2(sA[ct][3]);
        lsA += (p0 + p1) + (p2 + p3);
        uint2 pk;
        pk.x = pkbf16(p0, p1);
        pk.y = pkbf16(p2, p3);
        *reinterpret_cast<uint2*>(&St[w][lo16][ct * 16 + quad * 4]) = pk;
      }
    }

    // ---- PV: V fragments shared by both groups ----
    const bf16x8 pb0 = *reinterpret_cast<const bf16x8*>(&St[w][16 + lo16][quad * 8]);
    const bf16x8 pb1 = *reinterpret_cast<const bf16x8*>(&St[w][16 + lo16][32 + quad * 8]);
    const bf16x8 pa0 = *reinterpret_cast<const bf16x8*>(&St[w][lo16][quad * 8]);
    const bf16x8 pa1 = *reinterpret_cast<const bf16x8*>(&St[w][lo16][32 + quad * 8]);
    __builtin_amdgcn_s_setprio(1);
#pragma unroll
    for (int ct = 0; ct < 4; ++ct) {
      const bf16x8 vb0 = *reinterpret_cast<const bf16x8*>(&Vt[ct * 16 + lo16][quad * 8]);
      const bf16x8 vb1 = *reinterpret_cast<const bf16x8*>(&Vt[ct * 16 + lo16][32 + quad * 8]);
      oB[ct] = __builtin_amdgcn_mfma_f32_16x16x32_bf16(pb0, vb0, oB[ct], 0, 0, 0);
      oB[ct] = __builtin_amdgcn_mfma_f32_16x16x32_bf16(pb1, vb1, oB[ct], 0, 0, 0);
      if (liveA) {
        oA[ct] = __builtin_amdgcn_mfma_f32_16x16x32_bf16(pa0, vb0, oA[ct], 0, 0, 0);
        oA[ct] = __builtin_amdgcn_mfma_f32_16x16x32_bf16(pa1, vb1, oA[ct], 0, 0, 0);
      }
    }
    __builtin_amdgcn_s_setprio(0);
  }

  // ---- per-group l reduction (butterfly: every lane gets its column's sum) ----
  lsA += __shfl_xor(lsA, 16);
  lsA += __shfl_xor(lsA, 32);
  lsB += __shfl_xor(lsB, 16);
  lsB += __shfl_xor(lsB, 32);

  if (SPLIT && part != 0) {
    // ---- partial epilogue: raw f32 O + l to workspace (merged later) ----
    float* Pp = P + ((size_t)(part - 1) * 32 + hb) * (size_t)(1024 * 64);
    float* Lq = Lp + ((size_t)(part - 1) * 32 + hb) * 1024;
    const int qlA = q0 - 1024 + w * 32;    // partial chunks have q0 >= 1024
    if (quad == 0) {
      Lq[qlA + lo16] = lsA;
      Lq[qlA + 16 + lo16] = lsB;
    }
#pragma unroll
    for (int r = 0; r < 4; ++r) {
      float* pA = Pp + (size_t)(qlA + quad * 4 + r) * 64 + lo16;
      float* pB = Pp + (size_t)(qlA + 16 + quad * 4 + r) * 64 + lo16;
#pragma unroll
      for (int ct = 0; ct < 4; ++ct) {
        pA[ct * 16] = oA[ct][r];
        pB[ct * 16] = oB[ct][r];
      }
    }
    return;
  }

  // ---- direct epilogue (R3 verbatim) ----
  if (quad == 0) {
    Li[w][lo16] = 1.f / lsA;
    Li[w][16 + lo16] = 1.f / lsB;
  }
  __builtin_amdgcn_wave_barrier();
  const f32x4 invA = *reinterpret_cast<const f32x4*>(&Li[w][quad * 4]);
  const f32x4 invB = *reinterpret_cast<const f32x4*>(&Li[w][16 + quad * 4]);

#pragma unroll
  for (int r = 0; r < 4; ++r) {
    bf16* opA = O + (((size_t)(b * Hc + h) * Sc) + q0 + w * 32 + quad * 4 + r) * DKc + lo16;
    bf16* opB = opA + (size_t)16 * DKc;
#pragma unroll
    for (int ct = 0; ct < 4; ++ct) {
      opA[ct * 16] = __float2bfloat16(oA[ct][r] * invA[r]);
      opB[ct * 16] = __float2bfloat16(oB[ct][r] * invB[r]);
    }
  }
}

// ===========================================================================
// Merge the two k-half partials for chunks 8..15 (q in [1024,2048)):
// att[hb][1024+q][d] = (P0 + P1) / (l0 + l1). 2048 blocks x 256 thr x 4 elems.
// ===========================================================================
__global__ __launch_bounds__(256)
void merge_att(const float* __restrict__ P, const float* __restrict__ Lp,
               bf16* __restrict__ att) {
  const int e = blockIdx.x * 256 + threadIdx.x;   // 0 .. 524287
  const int d4 = (e & 15) * 4;
  const int q  = (e >> 4) & 1023;
  const int hb = e >> 14;                         // 0..31
  const size_t pi = ((size_t)hb * 1024 + q) * 64 + d4;
  const float4 a = *reinterpret_cast<const float4*>(P + pi);
  const float4 c = *reinterpret_cast<const float4*>(P + (size_t)2097152 + pi);
  const float inv = 1.f / (Lp[hb * 1024 + q] + Lp[32768 + hb * 1024 + q]);
  uint2 o;
  o.x = pkbf16((a.x + c.x) * inv, (a.y + c.y) * inv);
  o.y = pkbf16((a.z + c.z) * inv, (a.w + c.w) * inv);
  *reinterpret_cast<uint2*>(att + ((size_t)hb * 2048 + 1024 + q) * 64 + d4) = o;
}

// ===========================================================================
extern "C" void kernel_launch(void* const* d_in, const int* in_sizes, int n_in,
                              void* d_out, int out_size, void* d_ws, size_t ws_size,
                              hipStream_t stream) {
  (void)in_sizes; (void)out_size;
  const char* query = (const char*)d_in[0];
  const char* key_  = (const char*)d_in[1];
  const char* value = (const char*)d_in[2];
  const int wb = n_in - 8;   // weights/biases are the last 8 inputs
  const char* Wq = (const char*)d_in[wb + 0];
  const char* bq = (const char*)d_in[wb + 1];
  const char* Wk = (const char*)d_in[wb + 2];
  const char* bk = (const char*)d_in[wb + 3];
  const char* Wv = (const char*)d_in[wb + 4];
  const char* bv = (const char*)d_in[wb + 5];
  const char* Wo = (const char*)d_in[wb + 6];
  const char* bo = (const char*)d_in[wb + 7];

  char* ws = (char*)d_ws;
  bf16* Qs  = (bf16*)(ws);                         // 8 MiB
  bf16* Ks  = (bf16*)(ws + ((size_t)8  << 20));    // 8 MiB
  bf16* Vs  = (bf16*)(ws + ((size_t)16 << 20));    // 8 MiB
  bf16* att = (bf16*)(ws + ((size_t)24 << 20));    // 8 MiB
  unsigned short* Wt_all = (unsigned short*)(ws + ((size_t)32 << 20));  // 4 x 2 MiB
  unsigned short* bb_all = (unsigned short*)(ws + ((size_t)40 << 20));  // 8 KiB
  int* flag = (int*)(ws + ((size_t)40 << 20) + 16384);
  bf16* Qb = (bf16*)(ws + ((size_t)42 << 20));     // 8 MiB (converted inputs)
  bf16* Kb = (bf16*)(ws + ((size_t)50 << 20));
  bf16* Vb = (bf16*)(ws + ((size_t)58 << 20));
  // attn split-K partials overlay the (dead-after-qkv) Qb/Kb/Vb region:
  float* Pw = (float*)(ws + ((size_t)42 << 20));   // 2 x 8.39 MiB f32 (42..58.8M)
  float* Lw = (float*)(ws + ((size_t)59 << 20));   // 2 x 128 KiB f32
  const bool big_ws = ws_size >= ((size_t)66 << 20);

  if (big_ws) {
    prep_all<<<2564, 256, 0, stream>>>(Wq, Wk, Wv, Wo, Wt_all, bq, bk, bv, bo,
                                       bb_all, query, key_, value, Qb, Kb, Vb, flag);
    qkv_gemm_async<<<dim3(32, 16, 3), 256, 0, stream>>>(Qb, Kb, Vb, Wt_all, bb_all,
                                                        Qs, Ks, Vs);
    attn_mfma<1><<<dim3(768), 256, 0, stream>>>(Qs, Ks, Vs, att, Pw, Lw);
    merge_att<<<dim3(2048), 256, 0, stream>>>(Pw, Lw, att);
  } else {
    // fallback: grid 1028 covers transpose (0..1023) + bias/flag (1024..1027)
    prep_all<<<1028, 256, 0, stream>>>(Wq, Wk, Wv, Wo, Wt_all, bq, bk, bv, bo,
                                       bb_all, query, key_, value,
                                       (bf16*)att, (bf16*)att, (bf16*)att, flag);
    qkv_gemm<<<dim3(32, 8, 3), 256, 0, stream>>>(query, key_, value, Wt_all, bb_all,
                                                 Qs, Ks, Vs, flag);
    attn_mfma<0><<<dim3(512), 256, 0, stream>>>(Qs, Ks, Vs, att, Pw, Lw);
  }

  out_gemm_async<<<dim3(64, 8), 256, 0, stream>>>(att, Wt_all + (size_t)3 * Dc * Dc,
                                                  bb_all + 3 * Dc, (char*)d_out, flag);
}